// Round 2
// baseline (25386.394 us; speedup 1.0000x reference)
//
#include <hip/hip_runtime.h>
#include <hip/hip_bf16.h>
#include <cstdint>

#define B_  32
#define T_  1000
#define F_  161
#define H_  512
#define C_  62
#define BT_ 32000
#define TC  200          // time-chunk length
#define NCH 5            // number of chunks
#define MCH (B_ * TC)    // rows per chunk gemm = 6400

typedef __bf16 bf16x8 __attribute__((ext_vector_type(8)));
typedef float  f32x4  __attribute__((ext_vector_type(4)));
typedef unsigned short us8 __attribute__((ext_vector_type(8)));

__device__ __forceinline__ float b2f_lo(unsigned int u) {
    union { unsigned int i; float f; } v; v.i = u << 16; return v.f;
}
__device__ __forceinline__ float b2f_hi(unsigned int u) {
    union { unsigned int i; float f; } v; v.i = u & 0xffff0000u; return v.f;
}
__device__ __forceinline__ unsigned short f2b(float f) {
    unsigned int u = __float_as_uint(f);
    unsigned int r = u + 0x7fffu + ((u >> 16) & 1u);   // RNE
    return (unsigned short)(r >> 16);
}

// ---------------- conversion kernels ----------------

// x [BT,161] f32 -> xb [BT,192] bf16 (zero-pad K)
__global__ __launch_bounds__(256) void cvt_x_pad(const float* __restrict__ x,
                                                 unsigned short* __restrict__ xb) {
    int idx = blockIdx.x * 256 + threadIdx.x;
    if (idx >= BT_ * 192) return;
    int r = idx / 192, k = idx - r * 192;
    float v = (k < F_) ? x[(size_t)r * F_ + k] : 0.f;
    xb[idx] = f2b(v);
}

// dst[n*KP + k] = bf16(src[(k0+k)*N + n]) for k<K,n<N else 0.  dst is [NP][KP].
__global__ __launch_bounds__(256) void transpose_cvt(const float* __restrict__ src,
                                                     unsigned short* __restrict__ dst,
                                                     int K, int N, int k0, int KP, int NP) {
    int idx = blockIdx.x * 256 + threadIdx.x;
    if (idx >= NP * KP) return;
    int n = idx / KP, k = idx - n * KP;
    float v = (k < K && n < N) ? src[(size_t)(k0 + k) * N + n] : 0.f;
    dst[idx] = f2b(v);
}

// dst[k*N+n] = bf16(src[(k0+k)*N + n])   (row-major slice, recurrence candidate weights)
__global__ __launch_bounds__(256) void rowcvt(const float* __restrict__ src,
                                              unsigned short* __restrict__ dst,
                                              int K, int N, int k0) {
    int idx = blockIdx.x * 256 + threadIdx.x;
    if (idx >= K * N) return;
    int k = idx / N, n = idx - k * N;
    dst[idx] = f2b(src[(size_t)(k0 + k) * N + n]);
}

// gate-shuffled recurrent weights: thread t owns cols {2t,2t+1} of r and u.
__global__ __launch_bounds__(256) void gate_shuf(const float* __restrict__ wg,
                                                 unsigned int* __restrict__ dst) {
    int idx = blockIdx.x * 256 + threadIdx.x;   // over 512*256
    if (idx >= 512 * 256) return;
    int k = idx >> 8, t = idx & 255;
    const float* row = wg + (size_t)(512 + k) * 1024;
    unsigned int u0 = (unsigned int)f2b(row[2 * t]) | ((unsigned int)f2b(row[2 * t + 1]) << 16);
    unsigned int u1 = (unsigned int)f2b(row[512 + 2 * t]) | ((unsigned int)f2b(row[513 + 2 * t]) << 16);
    dst[(size_t)idx * 2]     = u0;
    dst[(size_t)idx * 2 + 1] = u1;
}

// bcat[d*1536 + c] = (c<1024 ? bg_d[c] : bc_d[c-1024])
__global__ __launch_bounds__(256) void biascat(const float* __restrict__ bg_f,
                                               const float* __restrict__ bc_f,
                                               const float* __restrict__ bg_b,
                                               const float* __restrict__ bc_b,
                                               float* __restrict__ bcat) {
    int idx = blockIdx.x * 256 + threadIdx.x;
    if (idx >= 2 * 1536) return;
    int d = idx / 1536, c = idx - d * 1536;
    const float* bg = d ? bg_b : bg_f;
    const float* bc = d ? bc_b : bc_f;
    bcat[idx] = (c < 1024) ? bg[c] : bc[c - 1024];
}

// ---------------- GEMM ----------------
// out[M,Nreal] = A[M,K] @ BT[N,K]^T (+bias) (opt relu)
// BM=128, BN=64, BK=64, 256 threads (4 waves, 2x2 wave grid, each wave 64x32 via 4x2 16x16 frags)
// AMAP:  A row r maps to global row (r/TC)*T_ + t0 + r%TC   (chunk gemm reading hB)
// OMODE: 0 = bf16 store, contiguous rows; 1 = f32 accumulate (+=) with chunk row remap

#define BM 128
#define BN 64
#define BK 64

template<bool RELU, int OMODE, bool AMAP>
__global__ __launch_bounds__(256) void gemm_bf16(const unsigned short* __restrict__ A,
                                                 const unsigned short* __restrict__ BT,
                                                 const float* __restrict__ bias,
                                                 void* __restrict__ Out,
                                                 int K, int Nreal, int t0) {
    __shared__ __align__(16) unsigned short As[BM * BK];
    __shared__ __align__(16) unsigned short Bs[BN * BK];
    const int tid  = threadIdx.x;
    const int lane = tid & 63;
    const int w    = tid >> 6;
    const int wm   = w & 1, wn = w >> 1;
    const int l15  = lane & 15, l4 = lane >> 4;
    const int m0   = blockIdx.x * BM;
    const int n0   = blockIdx.y * BN;

    // staging coords
    const int ar = tid >> 1, ac = (tid & 1) * 32;   // A: 128 rows, half-row each
    const int br = tid >> 2, bc = (tid & 3) * 16;   // B: 64 rows, quarter-row each

    size_t arow;
    {
        int r = m0 + ar;
        if (AMAP) { int rb = r / TC; int rt = r - rb * TC; arow = (size_t)rb * T_ + t0 + rt; }
        else      arow = (size_t)r;
    }

    f32x4 acc[4][2] = {};

    for (int kt = 0; kt < K; kt += BK) {
        if (kt) __syncthreads();
        {
            const unsigned short* ga = A + arow * K + kt + ac;
            us8* la = (us8*)(As + ar * BK + ac);
            #pragma unroll
            for (int j = 0; j < 4; ++j) la[j] = *(const us8*)(ga + 8 * j);
            const unsigned short* gb = BT + (size_t)(n0 + br) * K + kt + bc;
            us8* lb = (us8*)(Bs + br * BK + bc);
            #pragma unroll
            for (int j = 0; j < 2; ++j) lb[j] = *(const us8*)(gb + 8 * j);
        }
        __syncthreads();
        #pragma unroll
        for (int kk = 0; kk < BK; kk += 32) {
            bf16x8 af[4], bfr[2];
            #pragma unroll
            for (int m = 0; m < 4; ++m)
                af[m] = *(const bf16x8*)(As + (wm * 64 + m * 16 + l15) * BK + kk + l4 * 8);
            #pragma unroll
            for (int n = 0; n < 2; ++n)
                bfr[n] = *(const bf16x8*)(Bs + (wn * 32 + n * 16 + l15) * BK + kk + l4 * 8);
            #pragma unroll
            for (int m = 0; m < 4; ++m)
                #pragma unroll
                for (int n = 0; n < 2; ++n)
                    acc[m][n] = __builtin_amdgcn_mfma_f32_16x16x32_bf16(af[m], bfr[n], acc[m][n], 0, 0, 0);
        }
    }

    // epilogue: D row=(lane>>4)*4+r, col=lane&15
    const int rbase = m0 + wm * 64;
    const int cb    = n0 + wn * 32;
    #pragma unroll
    for (int m = 0; m < 4; ++m) {
        #pragma unroll
        for (int n = 0; n < 2; ++n) {
            int gc = cb + n * 16 + l15;
            if (gc < Nreal) {
                float bv = bias ? bias[gc] : 0.f;
                int gr0 = rbase + m * 16 + l4 * 4;
                #pragma unroll
                for (int r = 0; r < 4; ++r) {
                    float v = acc[m][n][r] + bv;
                    if (RELU) v = fmaxf(v, 0.f);
                    int gr = gr0 + r;
                    if (OMODE == 0) {
                        ((unsigned short*)Out)[(size_t)gr * Nreal + gc] = f2b(v);
                    } else {
                        int rb = gr / TC; int rt = gr - rb * TC;
                        size_t orow = (size_t)rb * T_ + t0 + rt;
                        ((float*)Out)[orow * Nreal + gc] += v;
                    }
                }
            }
        }
    }
}

// ---------------- GRU chunk: 64 blocks = (dir, batch), 256 threads, TC steps ----------------
// X layout per chunk row m=b*TC+tt: [0:512)=r-gate input, [512:1024)=u-gate, [1024:1536)=cand.
// fwd (dir 0): t = t0f + tt ascending; bwd (dir 1): t = t0b + tt descending.
// hstate[(dir*32+b)*512 + c] carries h across chunk launches. Thread t owns cols {2t,2t+1}.

__global__ __launch_bounds__(256) void gru_chunk(const unsigned int* __restrict__ wgs_f,
                                                 const unsigned short* __restrict__ wch_f,
                                                 const unsigned int* __restrict__ wgs_b,
                                                 const unsigned short* __restrict__ wch_b,
                                                 const unsigned short* __restrict__ Xf,
                                                 const unsigned short* __restrict__ Xb,
                                                 const int* __restrict__ seq_lens,
                                                 float* __restrict__ hstate,
                                                 unsigned short* __restrict__ of,
                                                 unsigned short* __restrict__ ob,
                                                 int t0f, int t0b, int init) {
    const int bid = blockIdx.x;
    const int dir = bid >> 5;
    const int b   = bid & 31;
    const int tid = threadIdx.x;
    const int c0  = 2 * tid;

    const unsigned int*   wgs = dir ? wgs_b : wgs_f;
    const unsigned short* wch = dir ? wch_b : wch_f;
    const unsigned short* X   = dir ? Xb    : Xf;
    unsigned short*       out = dir ? ob    : of;
    const int t0 = dir ? t0b : t0f;

    float* hst = hstate + (size_t)(dir * 32 + b) * 512;

    __shared__ float hsh[512];
    __shared__ float rhsh[512];
    if (init) { hsh[c0] = 0.f; hsh[c0 + 1] = 0.f; }
    else      { hsh[c0] = hst[c0]; hsh[c0 + 1] = hst[c0 + 1]; }
    __syncthreads();

    int L = seq_lens[b];
    L = L < 0 ? 0 : (L > T_ ? T_ : L);

    for (int i = 0; i < TC; ++i) {
        const int tt = dir ? (TC - 1 - i) : i;
        const int t  = t0 + tt;
        const size_t m = (size_t)b * TC + tt;

        if (t < L) {
            const unsigned short* xr = X + m * 1536;

            unsigned int xg01 = *(const unsigned int*)(xr + c0);
            unsigned int xg23 = *(const unsigned int*)(xr + 512 + c0);
            float g0 = b2f_lo(xg01), g1 = b2f_hi(xg01);
            float g2 = b2f_lo(xg23), g3 = b2f_hi(xg23);

            // gates: ru[c] = X[c] + sum_k h[k] * wg[H+k][c]
            #pragma unroll 4
            for (int k4 = 0; k4 < 128; ++k4) {
                float4 hk = *(const float4*)(&hsh[k4 * 4]);
                #pragma unroll
                for (int j = 0; j < 4; ++j) {
                    const unsigned int* wv = wgs + ((size_t)(k4 * 4 + j) * 256 + tid) * 2;
                    unsigned int wr = wv[0], wu = wv[1];
                    float h_j = (j == 0) ? hk.x : (j == 1) ? hk.y : (j == 2) ? hk.z : hk.w;
                    g0 = fmaf(h_j, b2f_lo(wr), g0);
                    g1 = fmaf(h_j, b2f_hi(wr), g1);
                    g2 = fmaf(h_j, b2f_lo(wu), g2);
                    g3 = fmaf(h_j, b2f_hi(wu), g3);
                }
            }
            float r0 = 1.f / (1.f + __expf(-g0));
            float r1 = 1.f / (1.f + __expf(-g1));
            float u0 = 1.f / (1.f + __expf(-g2));
            float u1 = 1.f / (1.f + __expf(-g3));
            float h0 = hsh[c0], h1 = hsh[c0 + 1];
            rhsh[c0]     = r0 * h0;
            rhsh[c0 + 1] = r1 * h1;
            __syncthreads();

            unsigned int xc01 = *(const unsigned int*)(xr + 1024 + c0);
            float a0 = b2f_lo(xc01), a1 = b2f_hi(xc01);
            #pragma unroll 4
            for (int k4 = 0; k4 < 128; ++k4) {
                float4 rk = *(const float4*)(&rhsh[k4 * 4]);
                #pragma unroll
                for (int j = 0; j < 4; ++j) {
                    unsigned int wc2 = *(const unsigned int*)(wch + (size_t)(k4 * 4 + j) * 512 + c0);
                    float r_j = (j == 0) ? rk.x : (j == 1) ? rk.y : (j == 2) ? rk.z : rk.w;
                    a0 = fmaf(r_j, b2f_lo(wc2), a0);
                    a1 = fmaf(r_j, b2f_hi(wc2), a1);
                }
            }
            float cc0 = tanhf(a0), cc1 = tanhf(a1);
            float hn0 = u0 * h0 + (1.f - u0) * cc0;
            float hn1 = u1 * h1 + (1.f - u1) * cc1;

            unsigned int pair = (unsigned int)f2b(hn0) | ((unsigned int)f2b(hn1) << 16);
            *(unsigned int*)(out + m * 512 + c0) = pair;
            hsh[c0] = hn0; hsh[c0 + 1] = hn1;
            __syncthreads();
        } else {
            *(unsigned int*)(out + m * 512 + c0) = 0u;   // uniform branch, no sync needed
        }
    }

    // persist state for next chunk (own values, no sync needed)
    hst[c0] = hsh[c0]; hst[c0 + 1] = hsh[c0 + 1];
}

// ---------------- launcher ----------------

extern "C" void kernel_launch(void* const* d_in, const int* in_sizes, int n_in,
                              void* d_out, int out_size, void* d_ws, size_t ws_size,
                              hipStream_t stream) {
    (void)in_sizes; (void)n_in; (void)out_size; (void)ws_size;
    const float* x    = (const float*)d_in[0];
    const int*   seq  = (const int*)  d_in[1];
    const float* w1   = (const float*)d_in[2];
    const float* b1   = (const float*)d_in[3];
    const float* w2   = (const float*)d_in[4];
    const float* b2   = (const float*)d_in[5];
    const float* wg_f = (const float*)d_in[6];
    const float* bg_f = (const float*)d_in[7];
    const float* wc_f = (const float*)d_in[8];
    const float* bc_f = (const float*)d_in[9];
    const float* wg_b = (const float*)d_in[10];
    const float* bg_b = (const float*)d_in[11];
    const float* wc_b = (const float*)d_in[12];
    const float* bc_b = (const float*)d_in[13];
    const float* wf   = (const float*)d_in[14];
    const float* bfv  = (const float*)d_in[15];

    char* p = (char*)d_ws;
    auto alloc = [&](size_t bytes) { char* q = p; p += (bytes + 255) & ~(size_t)255; return q; };

    // persistent weight buffers (~7.1 MB)
    unsigned short* w1T     = (unsigned short*)alloc(512 * 192 * 2);
    unsigned short* w2T     = (unsigned short*)alloc(512 * 512 * 2);
    unsigned short* wx_f    = (unsigned short*)alloc((size_t)1536 * 512 * 2);
    unsigned short* wx_b    = (unsigned short*)alloc((size_t)1536 * 512 * 2);
    unsigned short* wfT_top = (unsigned short*)alloc(64 * 512 * 2);
    unsigned short* wfT_bot = (unsigned short*)alloc(64 * 512 * 2);
    unsigned int*   wgs_f   = (unsigned int*)  alloc((size_t)512 * 256 * 2 * 4);
    unsigned short* wch_f   = (unsigned short*)alloc(512 * 512 * 2);
    unsigned int*   wgs_b   = (unsigned int*)  alloc((size_t)512 * 256 * 2 * 4);
    unsigned short* wch_b   = (unsigned short*)alloc(512 * 512 * 2);
    float*          bcat    = (float*)         alloc(2 * 1536 * 4);

    // hB persistent through chunk phase (32.8 MB)
    unsigned short* hB = (unsigned short*)alloc((size_t)BT_ * 512 * 2);

    // union region: {xb, h1} (phases 0-2) aliases {Xf, Xb, of, ob, hstate} (chunk phase)
    // sizes: xb+h1 = 45.06 MB  <=  Xf+Xb+of+ob+hstate = 52.56 MB
    char* U = alloc((size_t)MCH * 1536 * 2 * 2 + (size_t)MCH * 512 * 2 * 2 + 64 * 512 * 4);
    unsigned short* xb = (unsigned short*)U;                                  // 12,288,000 B
    unsigned short* h1 = (unsigned short*)(U + (size_t)BT_ * 192 * 2);        // 32,768,000 B
    unsigned short* Xf = (unsigned short*)U;                                  // 19,660,800 B
    unsigned short* Xb = (unsigned short*)(U + (size_t)MCH * 1536 * 2);
    unsigned short* of = (unsigned short*)(U + (size_t)MCH * 1536 * 2 * 2);   // 6,553,600 B
    unsigned short* ob = (unsigned short*)(U + (size_t)MCH * 1536 * 2 * 2 + (size_t)MCH * 512 * 2);
    float*       hstate = (float*)(U + (size_t)MCH * 1536 * 2 * 2 + (size_t)MCH * 512 * 2 * 2);

    // d_out = fwd-proj + bwd-proj accumulation target
    hipMemsetAsync(d_out, 0, (size_t)BT_ * C_ * 4, stream);

    // ---- weight prep ----
    transpose_cvt<<<(512 * 192) / 256, 256, 0, stream>>>(w1, w1T, 161, 512, 0, 192, 512);
    transpose_cvt<<<(512 * 512) / 256, 256, 0, stream>>>(w2, w2T, 512, 512, 0, 512, 512);
    transpose_cvt<<<(1024 * 512) / 256, 256, 0, stream>>>(wg_f, wx_f, 512, 1024, 0, 512, 1024);
    transpose_cvt<<<(512 * 512) / 256, 256, 0, stream>>>(wc_f, wx_f + (size_t)1024 * 512, 512, 512, 0, 512, 512);
    transpose_cvt<<<(1024 * 512) / 256, 256, 0, stream>>>(wg_b, wx_b, 512, 1024, 0, 512, 1024);
    transpose_cvt<<<(512 * 512) / 256, 256, 0, stream>>>(wc_b, wx_b + (size_t)1024 * 512, 512, 512, 0, 512, 512);
    transpose_cvt<<<(64 * 512) / 256, 256, 0, stream>>>(wf, wfT_top, 512, 62, 0, 512, 64);
    transpose_cvt<<<(64 * 512) / 256, 256, 0, stream>>>(wf, wfT_bot, 512, 62, 512, 512, 64);
    gate_shuf<<<512, 256, 0, stream>>>(wg_f, wgs_f);
    gate_shuf<<<512, 256, 0, stream>>>(wg_b, wgs_b);
    rowcvt<<<(512 * 512) / 256, 256, 0, stream>>>(wc_f, wch_f, 512, 512, 512);
    rowcvt<<<(512 * 512) / 256, 256, 0, stream>>>(wc_b, wch_b, 512, 512, 512);
    biascat<<<(2 * 1536 + 255) / 256, 256, 0, stream>>>(bg_f, bc_f, bg_b, bc_b, bcat);

    // ---- dense front-end ----
    cvt_x_pad<<<(BT_ * 192 + 255) / 256, 256, 0, stream>>>(x, xb);
    gemm_bf16<true, 0, false><<<dim3(BT_ / BM, 512 / BN), 256, 0, stream>>>(xb, w1T, b1, h1, 192, 512, 0);
    gemm_bf16<true, 0, false><<<dim3(BT_ / BM, 512 / BN), 256, 0, stream>>>(h1, w2T, b2, hB, 512, 512, 0);

    // ---- chunked BiGRU + projection ----
    for (int c = 0; c < NCH; ++c) {
        const int t0f = c * TC;
        const int t0b = (NCH - 1 - c) * TC;
        gemm_bf16<false, 0, true><<<dim3(MCH / BM, 1536 / BN), 256, 0, stream>>>(hB, wx_f, bcat,        Xf, 512, 1536, t0f);
        gemm_bf16<false, 0, true><<<dim3(MCH / BM, 1536 / BN), 256, 0, stream>>>(hB, wx_b, bcat + 1536, Xb, 512, 1536, t0b);
        gru_chunk<<<64, 256, 0, stream>>>(wgs_f, wch_f, wgs_b, wch_b, Xf, Xb, seq, hstate, of, ob,
                                          t0f, t0b, c == 0 ? 1 : 0);
        gemm_bf16<false, 1, false><<<dim3(MCH / BM, 1), 256, 0, stream>>>(of, wfT_top, bfv,     d_out, 512, C_, t0f);
        gemm_bf16<false, 1, false><<<dim3(MCH / BM, 1), 256, 0, stream>>>(ob, wfT_bot, nullptr, d_out, 512, C_, t0b);
    }
}

// Round 3
// 15318.358 us; speedup vs baseline: 1.6573x; 1.6573x over previous
//
#include <hip/hip_runtime.h>
#include <hip/hip_bf16.h>
#include <cstdint>

#define B_  32
#define T_  1000
#define F_  161
#define H_  512
#define C_  62
#define BT_ 32000
#define TC  200          // time-chunk length
#define NCH 5            // number of chunks
#define MCH (B_ * TC)    // rows per chunk gemm = 6400

typedef __bf16 bf16x8 __attribute__((ext_vector_type(8)));
typedef float  f32x4  __attribute__((ext_vector_type(4)));
typedef unsigned short us8 __attribute__((ext_vector_type(8)));

__device__ __forceinline__ float b2f_lo(unsigned int u) {
    union { unsigned int i; float f; } v; v.i = u << 16; return v.f;
}
__device__ __forceinline__ float b2f_hi(unsigned int u) {
    union { unsigned int i; float f; } v; v.i = u & 0xffff0000u; return v.f;
}
__device__ __forceinline__ float b2f(unsigned short s) {
    union { unsigned int i; float f; } v; v.i = (unsigned int)s << 16; return v.f;
}
__device__ __forceinline__ unsigned short f2b(float f) {
    unsigned int u = __float_as_uint(f);
    unsigned int r = u + 0x7fffu + ((u >> 16) & 1u);   // RNE
    return (unsigned short)(r >> 16);
}

// ---------------- conversion kernels ----------------

// x [BT,161] f32 -> xb [BT,192] bf16 (zero-pad K)
__global__ __launch_bounds__(256) void cvt_x_pad(const float* __restrict__ x,
                                                 unsigned short* __restrict__ xb) {
    int idx = blockIdx.x * 256 + threadIdx.x;
    if (idx >= BT_ * 192) return;
    int r = idx / 192, k = idx - r * 192;
    float v = (k < F_) ? x[(size_t)r * F_ + k] : 0.f;
    xb[idx] = f2b(v);
}

// dst[n*KP + k] = bf16(src[(k0+k)*N + n]) for k<K,n<N else 0.  dst is [NP][KP].
__global__ __launch_bounds__(256) void transpose_cvt(const float* __restrict__ src,
                                                     unsigned short* __restrict__ dst,
                                                     int K, int N, int k0, int KP, int NP) {
    int idx = blockIdx.x * 256 + threadIdx.x;
    if (idx >= NP * KP) return;
    int n = idx / KP, k = idx - n * KP;
    float v = (k < K && n < N) ? src[(size_t)(k0 + k) * N + n] : 0.f;
    dst[idx] = f2b(v);
}

// gate recurrent weights, packed for the 1024-thread gru block:
// wgp[k*512 + ti] = pack(wg[512+k][2ti], wg[512+k][2ti+1])   (ru space, cols 0..1023)
__global__ __launch_bounds__(256) void gate_shuf2(const float* __restrict__ wg,
                                                  unsigned int* __restrict__ dst) {
    int idx = blockIdx.x * 256 + threadIdx.x;   // over 512*512
    if (idx >= 512 * 512) return;
    int k = idx >> 9, ti = idx & 511;
    const float* row = wg + (size_t)(512 + k) * 1024;
    dst[idx] = (unsigned int)f2b(row[2 * ti]) | ((unsigned int)f2b(row[2 * ti + 1]) << 16);
}

// cand recurrent weights: wcp[k*256 + ti] = pack(wc[512+k][2ti], wc[512+k][2ti+1])
__global__ __launch_bounds__(256) void cand_shuf2(const float* __restrict__ wc,
                                                  unsigned int* __restrict__ dst) {
    int idx = blockIdx.x * 256 + threadIdx.x;   // over 512*256
    if (idx >= 512 * 256) return;
    int k = idx >> 8, ti = idx & 255;
    const float* row = wc + (size_t)(512 + k) * 512;
    dst[idx] = (unsigned int)f2b(row[2 * ti]) | ((unsigned int)f2b(row[2 * ti + 1]) << 16);
}

// bcat[d*1536 + c] = (c<1024 ? bg_d[c] : bc_d[c-1024])
__global__ __launch_bounds__(256) void biascat(const float* __restrict__ bg_f,
                                               const float* __restrict__ bc_f,
                                               const float* __restrict__ bg_b,
                                               const float* __restrict__ bc_b,
                                               float* __restrict__ bcat) {
    int idx = blockIdx.x * 256 + threadIdx.x;
    if (idx >= 2 * 1536) return;
    int d = idx / 1536, c = idx - d * 1536;
    const float* bg = d ? bg_b : bg_f;
    const float* bc = d ? bc_b : bc_f;
    bcat[idx] = (c < 1024) ? bg[c] : bc[c - 1024];
}

// ---------------- GEMM ----------------
// out[M,Nreal] = A[M,K] @ BT[N,K]^T (+bias) (opt relu)
// BM=128, BN=64, BK=64, 256 threads (4 waves, 2x2 wave grid, each wave 64x32 via 4x2 16x16 frags)
// AMAP:  A row r maps to global row (r/TC)*T_ + t0 + r%TC   (chunk gemm reading hB)
// OMODE: 0 = bf16 store, contiguous rows; 1 = f32 accumulate (+=) with chunk row remap

#define BM 128
#define BN 64
#define BK 64

template<bool RELU, int OMODE, bool AMAP>
__global__ __launch_bounds__(256) void gemm_bf16(const unsigned short* __restrict__ A,
                                                 const unsigned short* __restrict__ BT,
                                                 const float* __restrict__ bias,
                                                 void* __restrict__ Out,
                                                 int K, int Nreal, int t0) {
    __shared__ __align__(16) unsigned short As[BM * BK];
    __shared__ __align__(16) unsigned short Bs[BN * BK];
    const int tid  = threadIdx.x;
    const int lane = tid & 63;
    const int w    = tid >> 6;
    const int wm   = w & 1, wn = w >> 1;
    const int l15  = lane & 15, l4 = lane >> 4;
    const int m0   = blockIdx.x * BM;
    const int n0   = blockIdx.y * BN;

    // staging coords
    const int ar = tid >> 1, ac = (tid & 1) * 32;   // A: 128 rows, half-row each
    const int br = tid >> 2, bc = (tid & 3) * 16;   // B: 64 rows, quarter-row each

    size_t arow;
    {
        int r = m0 + ar;
        if (AMAP) { int rb = r / TC; int rt = r - rb * TC; arow = (size_t)rb * T_ + t0 + rt; }
        else      arow = (size_t)r;
    }

    f32x4 acc[4][2] = {};

    for (int kt = 0; kt < K; kt += BK) {
        if (kt) __syncthreads();
        {
            const unsigned short* ga = A + arow * K + kt + ac;
            us8* la = (us8*)(As + ar * BK + ac);
            #pragma unroll
            for (int j = 0; j < 4; ++j) la[j] = *(const us8*)(ga + 8 * j);
            const unsigned short* gb = BT + (size_t)(n0 + br) * K + kt + bc;
            us8* lb = (us8*)(Bs + br * BK + bc);
            #pragma unroll
            for (int j = 0; j < 2; ++j) lb[j] = *(const us8*)(gb + 8 * j);
        }
        __syncthreads();
        #pragma unroll
        for (int kk = 0; kk < BK; kk += 32) {
            bf16x8 af[4], bfr[2];
            #pragma unroll
            for (int m = 0; m < 4; ++m)
                af[m] = *(const bf16x8*)(As + (wm * 64 + m * 16 + l15) * BK + kk + l4 * 8);
            #pragma unroll
            for (int n = 0; n < 2; ++n)
                bfr[n] = *(const bf16x8*)(Bs + (wn * 32 + n * 16 + l15) * BK + kk + l4 * 8);
            #pragma unroll
            for (int m = 0; m < 4; ++m)
                #pragma unroll
                for (int n = 0; n < 2; ++n)
                    acc[m][n] = __builtin_amdgcn_mfma_f32_16x16x32_bf16(af[m], bfr[n], acc[m][n], 0, 0, 0);
        }
    }

    // epilogue: D row=(lane>>4)*4+r, col=lane&15
    const int rbase = m0 + wm * 64;
    const int cb    = n0 + wn * 32;
    #pragma unroll
    for (int m = 0; m < 4; ++m) {
        #pragma unroll
        for (int n = 0; n < 2; ++n) {
            int gc = cb + n * 16 + l15;
            if (gc < Nreal) {
                float bv = bias ? bias[gc] : 0.f;
                int gr0 = rbase + m * 16 + l4 * 4;
                #pragma unroll
                for (int r = 0; r < 4; ++r) {
                    float v = acc[m][n][r] + bv;
                    if (RELU) v = fmaxf(v, 0.f);
                    int gr = gr0 + r;
                    if (OMODE == 0) {
                        ((unsigned short*)Out)[(size_t)gr * Nreal + gc] = f2b(v);
                    } else {
                        int rb = gr / TC; int rt = gr - rb * TC;
                        size_t orow = (size_t)rb * T_ + t0 + rt;
                        ((float*)Out)[orow * Nreal + gc] += v;
                    }
                }
            }
        }
    }
}

// ---------------- GRU chunk: 64 blocks = (dir, batch), 1024 threads (16 waves), TC steps ----
// k-split reduction: gates: thread (half=tid>>9, ti=tid&511) accumulates outputs {2ti,2ti+1}
// over k in [half*256, half*256+256); candidate: thread (q=tid>>8, tq=tid&255) accumulates
// outputs {2tq,2tq+1} over k in [q*128, q*128+128). Partials combined via LDS.
// X layout per chunk row m: [0:512)=r-in, [512:1024)=u-in, [1024:1536)=cand-in.

__global__ __launch_bounds__(1024) void gru_chunk(const unsigned int* __restrict__ wgp_f,
                                                  const unsigned int* __restrict__ wcp_f,
                                                  const unsigned int* __restrict__ wgp_b,
                                                  const unsigned int* __restrict__ wcp_b,
                                                  const unsigned short* __restrict__ Xf,
                                                  const unsigned short* __restrict__ Xb,
                                                  const int* __restrict__ seq_lens,
                                                  float* __restrict__ hstate,
                                                  unsigned short* __restrict__ of,
                                                  unsigned short* __restrict__ ob,
                                                  int t0f, int t0b, int init) {
    const int bid = blockIdx.x;
    const int dir = bid >> 5;
    const int b   = bid & 31;
    const int tid = threadIdx.x;
    const int half = tid >> 9, ti = tid & 511;
    const int q    = tid >> 8, tq = tid & 255;

    const unsigned int*   wgp = dir ? wgp_b : wgp_f;
    const unsigned int*   wcp = dir ? wcp_b : wcp_f;
    const unsigned short* X   = dir ? Xb    : Xf;
    unsigned short*       out = dir ? ob    : of;
    const int t0 = dir ? t0b : t0f;

    float* hst = hstate + (size_t)(dir * 32 + b) * 512;

    __shared__ float hsh[512];
    __shared__ float rhsh[512];
    __shared__ float pg[2][512][2];
    __shared__ float pc[4][256][2];

    if (tid < 512) hsh[tid] = init ? 0.f : hst[tid];
    __syncthreads();

    int L = seq_lens[b];
    L = L < 0 ? 0 : (L > T_ ? T_ : L);

    const unsigned int* wg0 = wgp + (size_t)(half * 256) * 512 + ti;
    const unsigned int* wc0 = wcp + (size_t)(q * 128) * 256 + tq;
    const int kbg = half * 256;
    const int kbc = q * 128;

    for (int i = 0; i < TC; ++i) {
        const int tt = dir ? (TC - 1 - i) : i;
        const int t  = t0 + tt;
        const size_t m = (size_t)b * TC + tt;

        if (t < L) {
            const unsigned short* xr = X + m * 1536;

            // ---- gate partials ----
            float g0 = 0.f, g1 = 0.f;
            #pragma unroll 4
            for (int k4 = 0; k4 < 64; ++k4) {
                float4 hk = *(const float4*)(&hsh[kbg + k4 * 4]);
                #pragma unroll
                for (int j = 0; j < 4; ++j) {
                    unsigned int w = wg0[(size_t)(k4 * 4 + j) * 512];
                    float h_j = (j == 0) ? hk.x : (j == 1) ? hk.y : (j == 2) ? hk.z : hk.w;
                    g0 = fmaf(h_j, b2f_lo(w), g0);
                    g1 = fmaf(h_j, b2f_hi(w), g1);
                }
            }
            pg[half][ti][0] = g0;
            pg[half][ti][1] = g1;
            __syncthreads();

            // ---- gate combine: thread tid = gate output o ----
            float uval = 0.f;
            {
                int o = tid;
                float s = pg[0][o >> 1][o & 1] + pg[1][o >> 1][o & 1] + b2f(xr[o]);
                float v = 1.f / (1.f + __expf(-s));
                if (o < 512) rhsh[o] = v * hsh[o];
                else         uval = v;
            }
            __syncthreads();

            // ---- candidate partials ----
            float c0 = 0.f, c1 = 0.f;
            #pragma unroll 4
            for (int k4 = 0; k4 < 32; ++k4) {
                float4 rk = *(const float4*)(&rhsh[kbc + k4 * 4]);
                #pragma unroll
                for (int j = 0; j < 4; ++j) {
                    unsigned int w = wc0[(size_t)(k4 * 4 + j) * 256];
                    float r_j = (j == 0) ? rk.x : (j == 1) ? rk.y : (j == 2) ? rk.z : rk.w;
                    c0 = fmaf(r_j, b2f_lo(w), c0);
                    c1 = fmaf(r_j, b2f_hi(w), c1);
                }
            }
            pc[q][tq][0] = c0;
            pc[q][tq][1] = c1;
            __syncthreads();

            // ---- candidate combine + state update: thread 512+c owns col c ----
            if (tid >= 512) {
                int c = tid - 512;
                float s = pc[0][c >> 1][c & 1] + pc[1][c >> 1][c & 1]
                        + pc[2][c >> 1][c & 1] + pc[3][c >> 1][c & 1] + b2f(xr[1024 + c]);
                float cc = tanhf(s);
                float h0 = hsh[c];
                float hn = uval * h0 + (1.f - uval) * cc;
                out[m * 512 + c] = f2b(hn);
                hsh[c] = hn;    // sole reader of hsh[c] after gate phase is this thread
            }
            __syncthreads();
        } else {
            if (tid >= 512) out[m * 512 + (tid - 512)] = 0;   // block-uniform branch
        }
    }

    if (tid < 512) hst[tid] = hsh[tid];
}

// ---------------- launcher ----------------

extern "C" void kernel_launch(void* const* d_in, const int* in_sizes, int n_in,
                              void* d_out, int out_size, void* d_ws, size_t ws_size,
                              hipStream_t stream) {
    (void)in_sizes; (void)n_in; (void)out_size; (void)ws_size;
    const float* x    = (const float*)d_in[0];
    const int*   seq  = (const int*)  d_in[1];
    const float* w1   = (const float*)d_in[2];
    const float* b1   = (const float*)d_in[3];
    const float* w2   = (const float*)d_in[4];
    const float* b2   = (const float*)d_in[5];
    const float* wg_f = (const float*)d_in[6];
    const float* bg_f = (const float*)d_in[7];
    const float* wc_f = (const float*)d_in[8];
    const float* bc_f = (const float*)d_in[9];
    const float* wg_b = (const float*)d_in[10];
    const float* bg_b = (const float*)d_in[11];
    const float* wc_b = (const float*)d_in[12];
    const float* bc_b = (const float*)d_in[13];
    const float* wf   = (const float*)d_in[14];
    const float* bfv  = (const float*)d_in[15];

    char* p = (char*)d_ws;
    auto alloc = [&](size_t bytes) { char* q = p; p += (bytes + 255) & ~(size_t)255; return q; };

    // persistent weight buffers (~7.1 MB)
    unsigned short* w1T     = (unsigned short*)alloc(512 * 192 * 2);
    unsigned short* w2T     = (unsigned short*)alloc(512 * 512 * 2);
    unsigned short* wx_f    = (unsigned short*)alloc((size_t)1536 * 512 * 2);
    unsigned short* wx_b    = (unsigned short*)alloc((size_t)1536 * 512 * 2);
    unsigned short* wfT_top = (unsigned short*)alloc(64 * 512 * 2);
    unsigned short* wfT_bot = (unsigned short*)alloc(64 * 512 * 2);
    unsigned int*   wgp_f   = (unsigned int*)  alloc((size_t)512 * 512 * 4);
    unsigned int*   wcp_f   = (unsigned int*)  alloc((size_t)512 * 256 * 4);
    unsigned int*   wgp_b   = (unsigned int*)  alloc((size_t)512 * 512 * 4);
    unsigned int*   wcp_b   = (unsigned int*)  alloc((size_t)512 * 256 * 4);
    float*          bcat    = (float*)         alloc(2 * 1536 * 4);

    // hB persistent through chunk phase (32.8 MB)
    unsigned short* hB = (unsigned short*)alloc((size_t)BT_ * 512 * 2);

    // union region: {xb, h1} (front-end) aliases {Xf, Xb, of, ob, hstate} (chunk phase)
    char* U = alloc((size_t)MCH * 1536 * 2 * 2 + (size_t)MCH * 512 * 2 * 2 + 64 * 512 * 4);
    unsigned short* xb = (unsigned short*)U;
    unsigned short* h1 = (unsigned short*)(U + (size_t)BT_ * 192 * 2);
    unsigned short* Xf = (unsigned short*)U;
    unsigned short* Xb = (unsigned short*)(U + (size_t)MCH * 1536 * 2);
    unsigned short* of = (unsigned short*)(U + (size_t)MCH * 1536 * 2 * 2);
    unsigned short* ob = (unsigned short*)(U + (size_t)MCH * 1536 * 2 * 2 + (size_t)MCH * 512 * 2);
    float*       hstate = (float*)(U + (size_t)MCH * 1536 * 2 * 2 + (size_t)MCH * 512 * 2 * 2);

    // d_out = fwd-proj + bwd-proj accumulation target
    hipMemsetAsync(d_out, 0, (size_t)BT_ * C_ * 4, stream);

    // ---- weight prep ----
    transpose_cvt<<<(512 * 192) / 256, 256, 0, stream>>>(w1, w1T, 161, 512, 0, 192, 512);
    transpose_cvt<<<(512 * 512) / 256, 256, 0, stream>>>(w2, w2T, 512, 512, 0, 512, 512);
    transpose_cvt<<<(1024 * 512) / 256, 256, 0, stream>>>(wg_f, wx_f, 512, 1024, 0, 512, 1024);
    transpose_cvt<<<(512 * 512) / 256, 256, 0, stream>>>(wc_f, wx_f + (size_t)1024 * 512, 512, 512, 0, 512, 512);
    transpose_cvt<<<(1024 * 512) / 256, 256, 0, stream>>>(wg_b, wx_b, 512, 1024, 0, 512, 1024);
    transpose_cvt<<<(512 * 512) / 256, 256, 0, stream>>>(wc_b, wx_b + (size_t)1024 * 512, 512, 512, 0, 512, 512);
    transpose_cvt<<<(64 * 512) / 256, 256, 0, stream>>>(wf, wfT_top, 512, 62, 0, 512, 64);
    transpose_cvt<<<(64 * 512) / 256, 256, 0, stream>>>(wf, wfT_bot, 512, 62, 512, 512, 64);
    gate_shuf2<<<(512 * 512) / 256, 256, 0, stream>>>(wg_f, wgp_f);
    gate_shuf2<<<(512 * 512) / 256, 256, 0, stream>>>(wg_b, wgp_b);
    cand_shuf2<<<(512 * 256) / 256, 256, 0, stream>>>(wc_f, wcp_f);
    cand_shuf2<<<(512 * 256) / 256, 256, 0, stream>>>(wc_b, wcp_b);
    biascat<<<(2 * 1536 + 255) / 256, 256, 0, stream>>>(bg_f, bc_f, bg_b, bc_b, bcat);

    // ---- dense front-end ----
    cvt_x_pad<<<(BT_ * 192 + 255) / 256, 256, 0, stream>>>(x, xb);
    gemm_bf16<true, 0, false><<<dim3(BT_ / BM, 512 / BN), 256, 0, stream>>>(xb, w1T, b1, h1, 192, 512, 0);
    gemm_bf16<true, 0, false><<<dim3(BT_ / BM, 512 / BN), 256, 0, stream>>>(h1, w2T, b2, hB, 512, 512, 0);

    // ---- chunked BiGRU + projection ----
    for (int c = 0; c < NCH; ++c) {
        const int t0f = c * TC;
        const int t0b = (NCH - 1 - c) * TC;
        gemm_bf16<false, 0, true><<<dim3(MCH / BM, 1536 / BN), 256, 0, stream>>>(hB, wx_f, bcat,        Xf, 512, 1536, t0f);
        gemm_bf16<false, 0, true><<<dim3(MCH / BM, 1536 / BN), 256, 0, stream>>>(hB, wx_b, bcat + 1536, Xb, 512, 1536, t0b);
        gru_chunk<<<64, 1024, 0, stream>>>(wgp_f, wcp_f, wgp_b, wcp_b, Xf, Xb, seq, hstate, of, ob,
                                           t0f, t0b, c == 0 ? 1 : 0);
        gemm_bf16<false, 1, false><<<dim3(MCH / BM, 1), 256, 0, stream>>>(of, wfT_top, bfv,     d_out, 512, C_, t0f);
        gemm_bf16<false, 1, false><<<dim3(MCH / BM, 1), 256, 0, stream>>>(ob, wfT_bot, nullptr, d_out, 512, C_, t0b);
    }
}

// Round 5
// 13848.602 us; speedup vs baseline: 1.8331x; 1.1061x over previous
//
#include <hip/hip_runtime.h>
#include <hip/hip_bf16.h>
#include <cstdint>

#define B_  32
#define T_  1000
#define F_  161
#define H_  512
#define C_  62
#define BT_ 32000
#define TC  200          // time-chunk length
#define NCH 5            // number of chunks
#define MCH (B_ * TC)    // rows per chunk gemm = 6400
#define NB_ 32           // gru grid blocks (2 dirs x 16 col-groups)

typedef __bf16 bf16x8 __attribute__((ext_vector_type(8)));
typedef float  f32x4  __attribute__((ext_vector_type(4)));
typedef unsigned short us8 __attribute__((ext_vector_type(8)));

__device__ __forceinline__ float b2f(unsigned short s) {
    union { unsigned int i; float f; } v; v.i = (unsigned int)s << 16; return v.f;
}
__device__ __forceinline__ unsigned short f2b(float f) {
    unsigned int u = __float_as_uint(f);
    unsigned int r = u + 0x7fffu + ((u >> 16) & 1u);   // RNE
    return (unsigned short)(r >> 16);
}

// ---------------- conversion kernels ----------------

// x [BT,161] f32 -> xb [BT,192] bf16 (zero-pad K)
__global__ __launch_bounds__(256) void cvt_x_pad(const float* __restrict__ x,
                                                 unsigned short* __restrict__ xb) {
    int idx = blockIdx.x * 256 + threadIdx.x;
    if (idx >= BT_ * 192) return;
    int r = idx / 192, k = idx - r * 192;
    float v = (k < F_) ? x[(size_t)r * F_ + k] : 0.f;
    xb[idx] = f2b(v);
}

// dst[n*KP + k] = bf16(src[(k0+k)*N + n]) for k<K,n<N else 0.  dst is [NP][KP].
__global__ __launch_bounds__(256) void transpose_cvt(const float* __restrict__ src,
                                                     unsigned short* __restrict__ dst,
                                                     int K, int N, int k0, int KP, int NP) {
    int idx = blockIdx.x * 256 + threadIdx.x;
    if (idx >= NP * KP) return;
    int n = idx / KP, k = idx - n * KP;
    float v = (k < K && n < N) ? src[(size_t)(k0 + k) * N + n] : 0.f;
    dst[idx] = f2b(v);
}

// bcat[d*1536 + c] = (c<1024 ? bg_d[c] : bc_d[c-1024])
__global__ __launch_bounds__(256) void biascat(const float* __restrict__ bg_f,
                                               const float* __restrict__ bc_f,
                                               const float* __restrict__ bg_b,
                                               const float* __restrict__ bc_b,
                                               float* __restrict__ bcat) {
    int idx = blockIdx.x * 256 + threadIdx.x;
    if (idx >= 2 * 1536) return;
    int d = idx / 1536, c = idx - d * 1536;
    const float* bg = d ? bg_b : bg_f;
    const float* bc = d ? bc_b : bc_f;
    bcat[idx] = (c < 1024) ? bg[c] : bc[c - 1024];
}

// ---------------- GEMM ----------------
// out[M,Nreal] = A[M,K] @ BT[N,K]^T (+bias) (opt relu)
// AMAP:  A row r maps to global row (r/TC)*T_ + t0 + r%TC   (chunk gemm reading hB)
// OMODE: 0 = bf16 store, contiguous rows; 1 = f32 accumulate (+=) with chunk row remap

#define BM 128
#define BN 64
#define BK 64

template<bool RELU, int OMODE, bool AMAP>
__global__ __launch_bounds__(256) void gemm_bf16(const unsigned short* __restrict__ A,
                                                 const unsigned short* __restrict__ BT,
                                                 const float* __restrict__ bias,
                                                 void* __restrict__ Out,
                                                 int K, int Nreal, int t0) {
    __shared__ __align__(16) unsigned short As[BM * BK];
    __shared__ __align__(16) unsigned short Bs[BN * BK];
    const int tid  = threadIdx.x;
    const int lane = tid & 63;
    const int w    = tid >> 6;
    const int wm   = w & 1, wn = w >> 1;
    const int l15  = lane & 15, l4 = lane >> 4;
    const int m0   = blockIdx.x * BM;
    const int n0   = blockIdx.y * BN;

    const int ar = tid >> 1, ac = (tid & 1) * 32;
    const int br = tid >> 2, bc = (tid & 3) * 16;

    size_t arow;
    {
        int r = m0 + ar;
        if (AMAP) { int rb = r / TC; int rt = r - rb * TC; arow = (size_t)rb * T_ + t0 + rt; }
        else      arow = (size_t)r;
    }

    f32x4 acc[4][2] = {};

    for (int kt = 0; kt < K; kt += BK) {
        if (kt) __syncthreads();
        {
            const unsigned short* ga = A + arow * K + kt + ac;
            us8* la = (us8*)(As + ar * BK + ac);
            #pragma unroll
            for (int j = 0; j < 4; ++j) la[j] = *(const us8*)(ga + 8 * j);
            const unsigned short* gb = BT + (size_t)(n0 + br) * K + kt + bc;
            us8* lb = (us8*)(Bs + br * BK + bc);
            #pragma unroll
            for (int j = 0; j < 2; ++j) lb[j] = *(const us8*)(gb + 8 * j);
        }
        __syncthreads();
        #pragma unroll
        for (int kk = 0; kk < BK; kk += 32) {
            bf16x8 af[4], bfr[2];
            #pragma unroll
            for (int m = 0; m < 4; ++m)
                af[m] = *(const bf16x8*)(As + (wm * 64 + m * 16 + l15) * BK + kk + l4 * 8);
            #pragma unroll
            for (int n = 0; n < 2; ++n)
                bfr[n] = *(const bf16x8*)(Bs + (wn * 32 + n * 16 + l15) * BK + kk + l4 * 8);
            #pragma unroll
            for (int m = 0; m < 4; ++m)
                #pragma unroll
                for (int n = 0; n < 2; ++n)
                    acc[m][n] = __builtin_amdgcn_mfma_f32_16x16x32_bf16(af[m], bfr[n], acc[m][n], 0, 0, 0);
        }
    }

    const int rbase = m0 + wm * 64;
    const int cb    = n0 + wn * 32;
    #pragma unroll
    for (int m = 0; m < 4; ++m) {
        #pragma unroll
        for (int n = 0; n < 2; ++n) {
            int gc = cb + n * 16 + l15;
            if (gc < Nreal) {
                float bv = bias ? bias[gc] : 0.f;
                int gr0 = rbase + m * 16 + l4 * 4;
                #pragma unroll
                for (int r = 0; r < 4; ++r) {
                    float v = acc[m][n][r] + bv;
                    if (RELU) v = fmaxf(v, 0.f);
                    int gr = gr0 + r;
                    if (OMODE == 0) {
                        ((unsigned short*)Out)[(size_t)gr * Nreal + gc] = f2b(v);
                    } else {
                        int rb = gr / TC; int rt = gr - rb * TC;
                        size_t orow = (size_t)rb * T_ + t0 + rt;
                        ((float*)Out)[orow * Nreal + gc] += v;
                    }
                }
            }
        }
    }
}

// ---------------- persistent BiGRU chunk kernel ----------------
// 32 blocks = 2 dirs x 16 col-groups, 512 threads (8 waves). RECURRENT weights (wh = rows
// 512.. of wg/wc, transposed) LDS-resident. Block (dir,g): gate cols [64g,64g+64) of
// ru-space; cand cols [32g,32g+32).
// Per step: stage h->LDS, MFMA gates, sigma (g<8 -> write r*h slice; g>=8 -> write u slice),
// device barrier, stage rh->LDS, MFMA cand, tanh + masked h update + out write, barrier.
// h state f32 in h_glob. Barrier: monotonic counter, target = NB_*(base + phase + 1).

__device__ __forceinline__ void gbar(unsigned int* cnt, unsigned int target) {
    __syncthreads();
    if (threadIdx.x == 0) {
        __threadfence();
        __hip_atomic_fetch_add(cnt, 1u, __ATOMIC_RELEASE, __HIP_MEMORY_SCOPE_AGENT);
        while (__hip_atomic_load(cnt, __ATOMIC_ACQUIRE, __HIP_MEMORY_SCOPE_AGENT) < target)
            __builtin_amdgcn_s_sleep(1);
    }
    __syncthreads();
}

__global__ __launch_bounds__(512) void gru_persist(const unsigned short* __restrict__ wh_f,
                                                   const unsigned short* __restrict__ wh_b,
                                                   const unsigned short* __restrict__ Xf,
                                                   const unsigned short* __restrict__ Xb,
                                                   const int* __restrict__ seq_lens,
                                                   float* __restrict__ h_glob,
                                                   unsigned short* __restrict__ rh_glob,
                                                   float* __restrict__ u_glob,
                                                   unsigned int* __restrict__ sync_cnt,
                                                   unsigned short* __restrict__ of,
                                                   unsigned short* __restrict__ ob,
                                                   int t0f, int t0b, int base) {
    __shared__ __align__(16) unsigned short WG[64 * 512];   // gate h-weight slice [col][k], swizzled
    __shared__ __align__(16) unsigned short WC[32 * 512];   // cand h-weight slice [col][k], swizzled
    __shared__ __align__(16) unsigned short STG[32 * 512];  // h (phase1) / rh (phase2), swizzled
    __shared__ __align__(16) unsigned short XGs[32 * 64];   // x-gate slice [b][64]
    __shared__ __align__(16) unsigned short XCs[32 * 32];   // x-cand slice [b][32]
    __shared__ int Ls[32];

    const int bid = blockIdx.x;
    const int dir = bid >> 4;
    const int g   = bid & 15;
    const int tid = threadIdx.x;
    const int lane = tid & 63;
    const int w   = tid >> 6;
    const int l15 = lane & 15, l4 = lane >> 4;

    const unsigned short* wh = dir ? wh_b : wh_f;
    const unsigned short* X  = dir ? Xb : Xf;
    unsigned short* out      = dir ? ob : of;
    const int t0 = dir ? t0b : t0f;
    float*          hg  = h_glob  + (size_t)dir * 32 * 512;
    unsigned short* rhg = rh_glob + (size_t)dir * 32 * 512;
    float*          ug  = u_glob  + (size_t)dir * 32 * 512;
    const bool is_r = (g < 8);

    // ---- load recurrent weight slices into LDS (swizzled: byte ^= (col&7)<<4) ----
    for (int j = tid; j < 4096; j += 512) {
        int col = j >> 6, ck = j & 63;
        int dstb = col * 1024 + ((ck * 16) ^ ((col & 7) << 4));
        *(us8*)((char*)WG + dstb) = *(const us8*)(wh + (size_t)(64 * g + col) * 512 + ck * 8);
    }
    for (int j = tid; j < 2048; j += 512) {
        int col = j >> 6, ck = j & 63;
        int dstb = col * 1024 + ((ck * 16) ^ ((col & 7) << 4));
        *(us8*)((char*)WC + dstb) = *(const us8*)(wh + (size_t)(1024 + 32 * g + col) * 512 + ck * 8);
    }
    if (tid < 32) {
        int L = seq_lens[tid];
        Ls[tid] = L < 0 ? 0 : (L > T_ ? T_ : L);
    }

    const int mt = w & 1, nt = w >> 1;           // phase1 tile (8 waves: 2x4)
    const int mt2 = w & 1, nt2 = (w >> 1) & 1;   // phase2 tile (waves 0-3: 2x2)

    for (int i = 0; i < TC; ++i) {
        const int tt = dir ? (TC - 1 - i) : i;
        const int t  = t0 + tt;

        // ---- stage h (f32 -> bf16, swizzled) and x-gate slice ----
        for (int j = tid; j < 2048; j += 512) {
            int row = j >> 6, ck = j & 63;
            const float* src = hg + row * 512 + ck * 8;
            us8 v;
            #pragma unroll
            for (int e = 0; e < 8; ++e) v[e] = f2b(src[e]);
            int dstb = row * 1024 + ((ck * 16) ^ ((row & 7) << 4));
            *(us8*)((char*)STG + dstb) = v;
        }
        if (tid < 256) {
            int b = tid >> 3, part = tid & 7;
            *(us8*)(XGs + b * 64 + part * 8) =
                *(const us8*)(X + ((size_t)b * TC + tt) * 1536 + 64 * g + part * 8);
        }
        __syncthreads();

        // ---- gates MFMA: [32,512] @ [512,64] ----
        f32x4 acc = {};
        {
            const int arow = mt * 16 + l15;
            const int bcol = nt * 16 + l15;
            const int sa = (arow & 7) << 4, sb = (bcol & 7) << 4;
            const char* pa = (const char*)STG + arow * 1024;
            const char* pb = (const char*)WG + bcol * 1024;
            #pragma unroll
            for (int kk = 0; kk < 16; ++kk) {
                int kb = kk * 64 + l4 * 16;
                bf16x8 a  = *(const bf16x8*)(pa + (kb ^ sa));
                bf16x8 bf = *(const bf16x8*)(pb + (kb ^ sb));
                acc = __builtin_amdgcn_mfma_f32_16x16x32_bf16(a, bf, acc, 0, 0, 0);
            }
        }
        {
            const int colL = nt * 16 + l15;
            const int col_ru = 64 * g + colL;
            #pragma unroll
            for (int r = 0; r < 4; ++r) {
                int row = mt * 16 + l4 * 4 + r;
                float s = acc[r] + b2f(XGs[row * 64 + colL]);
                float sg = 1.f / (1.f + __expf(-s));
                if (is_r) {
                    unsigned short ho = *(const unsigned short*)((const char*)STG + row * 1024 +
                                            ((col_ru * 2) ^ ((row & 7) << 4)));
                    rhg[row * 512 + col_ru] = f2b(sg * b2f(ho));
                } else {
                    ug[row * 512 + (col_ru - 512)] = sg;
                }
            }
        }
        gbar(sync_cnt, (unsigned)(NB_ * (base + 2 * i + 1)));

        // ---- stage rh (bf16, swizzled) and x-cand slice ----
        for (int j = tid; j < 2048; j += 512) {
            int row = j >> 6, ck = j & 63;
            int dstb = row * 1024 + ((ck * 16) ^ ((row & 7) << 4));
            *(us8*)((char*)STG + dstb) = *(const us8*)(rhg + row * 512 + ck * 8);
        }
        if (tid < 128) {
            int b = tid >> 2, part = tid & 3;
            *(us8*)(XCs + b * 32 + part * 8) =
                *(const us8*)(X + ((size_t)b * TC + tt) * 1536 + 1024 + 32 * g + part * 8);
        }
        __syncthreads();

        // ---- candidate MFMA: [32,512] @ [512,32], waves 0-3 ----
        if (w < 4) {
            f32x4 acc2 = {};
            const int arow = mt2 * 16 + l15;
            const int bcol = nt2 * 16 + l15;
            const int sa = (arow & 7) << 4, sb = (bcol & 7) << 4;
            const char* pa = (const char*)STG + arow * 1024;
            const char* pb = (const char*)WC + bcol * 1024;
            #pragma unroll
            for (int kk = 0; kk < 16; ++kk) {
                int kb = kk * 64 + l4 * 16;
                bf16x8 a  = *(const bf16x8*)(pa + (kb ^ sa));
                bf16x8 bf = *(const bf16x8*)(pb + (kb ^ sb));
                acc2 = __builtin_amdgcn_mfma_f32_16x16x32_bf16(a, bf, acc2, 0, 0, 0);
            }
            const int colL = nt2 * 16 + l15;
            const int col_c = 32 * g + colL;
            #pragma unroll
            for (int r = 0; r < 4; ++r) {
                int row = mt2 * 16 + l4 * 4 + r;
                float s = acc2[r] + b2f(XCs[row * 32 + colL]);
                float cv = tanhf(s);
                float uu = ug[row * 512 + col_c];
                float ho = hg[row * 512 + col_c];
                bool act = (t < Ls[row]);
                float hn = act ? (uu * ho + (1.f - uu) * cv) : ho;
                out[((size_t)row * TC + tt) * 512 + col_c] = act ? f2b(hn) : (unsigned short)0;
                hg[row * 512 + col_c] = hn;
            }
        }
        gbar(sync_cnt, (unsigned)(NB_ * (base + 2 * i + 2)));
    }
}

// ---------------- launcher ----------------

extern "C" void kernel_launch(void* const* d_in, const int* in_sizes, int n_in,
                              void* d_out, int out_size, void* d_ws, size_t ws_size,
                              hipStream_t stream) {
    (void)in_sizes; (void)n_in; (void)out_size; (void)ws_size;
    const float* x    = (const float*)d_in[0];
    const int*   seq  = (const int*)  d_in[1];
    const float* w1   = (const float*)d_in[2];
    const float* b1   = (const float*)d_in[3];
    const float* w2   = (const float*)d_in[4];
    const float* b2   = (const float*)d_in[5];
    const float* wg_f = (const float*)d_in[6];
    const float* bg_f = (const float*)d_in[7];
    const float* wc_f = (const float*)d_in[8];
    const float* bc_f = (const float*)d_in[9];
    const float* wg_b = (const float*)d_in[10];
    const float* bg_b = (const float*)d_in[11];
    const float* wc_b = (const float*)d_in[12];
    const float* bc_b = (const float*)d_in[13];
    const float* wf   = (const float*)d_in[14];
    const float* bfv  = (const float*)d_in[15];

    char* p = (char*)d_ws;
    auto alloc = [&](size_t bytes) { char* q = p; p += (bytes + 255) & ~(size_t)255; return q; };

    // persistent weight buffers
    unsigned short* w1T     = (unsigned short*)alloc(512 * 192 * 2);
    unsigned short* w2T     = (unsigned short*)alloc(512 * 512 * 2);
    unsigned short* wx_f    = (unsigned short*)alloc((size_t)1536 * 512 * 2);   // x-half (k0=0)
    unsigned short* wx_b    = (unsigned short*)alloc((size_t)1536 * 512 * 2);
    unsigned short* wh_f    = (unsigned short*)alloc((size_t)1536 * 512 * 2);   // h-half (k0=512)
    unsigned short* wh_b    = (unsigned short*)alloc((size_t)1536 * 512 * 2);
    unsigned short* wfT_top = (unsigned short*)alloc(64 * 512 * 2);
    unsigned short* wfT_bot = (unsigned short*)alloc(64 * 512 * 2);
    float*          bcat    = (float*)         alloc(2 * 1536 * 4);

    // hB persistent through chunk phase (32.8 MB)
    unsigned short* hB = (unsigned short*)alloc((size_t)BT_ * 512 * 2);

    // union region: {xb, h1} (front-end) aliases {Xf, Xb, of, ob} (chunk phase)
    char* U = alloc((size_t)MCH * 1536 * 2 * 2 + (size_t)MCH * 512 * 2 * 2);
    unsigned short* xb = (unsigned short*)U;
    unsigned short* h1 = (unsigned short*)(U + (size_t)BT_ * 192 * 2);
    unsigned short* Xf = (unsigned short*)U;
    unsigned short* Xb = (unsigned short*)(U + (size_t)MCH * 1536 * 2);
    unsigned short* of = (unsigned short*)(U + (size_t)MCH * 1536 * 2 * 2);
    unsigned short* ob = (unsigned short*)(U + (size_t)MCH * 1536 * 2 * 2 + (size_t)MCH * 512 * 2);

    // GRU state/comm (outside union; sync+h zeroed each call)
    unsigned int*   sync_cnt = (unsigned int*)  alloc(256);
    float*          h_glob   = (float*)         alloc((size_t)2 * 32 * 512 * 4);
    unsigned short* rh_glob  = (unsigned short*)alloc((size_t)2 * 32 * 512 * 2);
    float*          u_glob   = (float*)         alloc((size_t)2 * 32 * 512 * 4);

    hipMemsetAsync(d_out, 0, (size_t)BT_ * C_ * 4, stream);
    hipMemsetAsync(sync_cnt, 0, 256 + (size_t)2 * 32 * 512 * 4, stream);  // sync + h_glob (contiguous)

    // ---- weight prep ----
    transpose_cvt<<<(512 * 192) / 256, 256, 0, stream>>>(w1, w1T, 161, 512, 0, 192, 512);
    transpose_cvt<<<(512 * 512) / 256, 256, 0, stream>>>(w2, w2T, 512, 512, 0, 512, 512);
    // x-halves (k0=0): feed the per-chunk input GEMMs
    transpose_cvt<<<(1024 * 512) / 256, 256, 0, stream>>>(wg_f, wx_f, 512, 1024, 0, 512, 1024);
    transpose_cvt<<<(512 * 512) / 256, 256, 0, stream>>>(wc_f, wx_f + (size_t)1024 * 512, 512, 512, 0, 512, 512);
    transpose_cvt<<<(1024 * 512) / 256, 256, 0, stream>>>(wg_b, wx_b, 512, 1024, 0, 512, 1024);
    transpose_cvt<<<(512 * 512) / 256, 256, 0, stream>>>(wc_b, wx_b + (size_t)1024 * 512, 512, 512, 0, 512, 512);
    // h-halves (k0=512): feed the persistent recurrence
    transpose_cvt<<<(1024 * 512) / 256, 256, 0, stream>>>(wg_f, wh_f, 512, 1024, 512, 512, 1024);
    transpose_cvt<<<(512 * 512) / 256, 256, 0, stream>>>(wc_f, wh_f + (size_t)1024 * 512, 512, 512, 512, 512, 512);
    transpose_cvt<<<(1024 * 512) / 256, 256, 0, stream>>>(wg_b, wh_b, 512, 1024, 512, 512, 1024);
    transpose_cvt<<<(512 * 512) / 256, 256, 0, stream>>>(wc_b, wh_b + (size_t)1024 * 512, 512, 512, 512, 512, 512);
    transpose_cvt<<<(64 * 512) / 256, 256, 0, stream>>>(wf, wfT_top, 512, 62, 0, 512, 64);
    transpose_cvt<<<(64 * 512) / 256, 256, 0, stream>>>(wf, wfT_bot, 512, 62, 512, 512, 64);
    biascat<<<(2 * 1536 + 255) / 256, 256, 0, stream>>>(bg_f, bc_f, bg_b, bc_b, bcat);

    // ---- dense front-end ----
    cvt_x_pad<<<(BT_ * 192 + 255) / 256, 256, 0, stream>>>(x, xb);
    gemm_bf16<true, 0, false><<<dim3(BT_ / BM, 512 / BN), 256, 0, stream>>>(xb, w1T, b1, h1, 192, 512, 0);
    gemm_bf16<true, 0, false><<<dim3(BT_ / BM, 512 / BN), 256, 0, stream>>>(h1, w2T, b2, hB, 512, 512, 0);

    // ---- chunked BiGRU + projection ----
    for (int c = 0; c < NCH; ++c) {
        const int t0f = c * TC;
        const int t0b = (NCH - 1 - c) * TC;
        gemm_bf16<false, 0, true><<<dim3(MCH / BM, 1536 / BN), 256, 0, stream>>>(hB, wx_f, bcat,        Xf, 512, 1536, t0f);
        gemm_bf16<false, 0, true><<<dim3(MCH / BM, 1536 / BN), 256, 0, stream>>>(hB, wx_b, bcat + 1536, Xb, 512, 1536, t0b);
        gru_persist<<<NB_, 512, 0, stream>>>(wh_f, wh_b, Xf, Xb, seq, h_glob, rh_glob, u_glob,
                                             sync_cnt, of, ob, t0f, t0b, c * 2 * TC);
        gemm_bf16<false, 1, false><<<dim3(MCH / BM, 1), 256, 0, stream>>>(of, wfT_top, bfv,     d_out, 512, C_, t0f);
        gemm_bf16<false, 1, false><<<dim3(MCH / BM, 1), 256, 0, stream>>>(ob, wfT_bot, nullptr, d_out, 512, C_, t0b);
    }
}

// Round 7
// 12915.462 us; speedup vs baseline: 1.9656x; 1.0722x over previous
//
#include <hip/hip_runtime.h>
#include <hip/hip_bf16.h>
#include <cstdint>

#define B_  32
#define T_  1000
#define F_  161
#define H_  512
#define C_  62
#define BT_ 32000
#define TC  200          // time-chunk length
#define NCH 5            // number of chunks
#define MCH (B_ * TC)    // rows per chunk gemm = 6400
#define NB_ 32           // gru grid blocks (2 dirs x 16 col-groups)

typedef __bf16 bf16x8 __attribute__((ext_vector_type(8)));
typedef float  f32x4  __attribute__((ext_vector_type(4)));
typedef unsigned short us8 __attribute__((ext_vector_type(8)));

__device__ __forceinline__ float b2f(unsigned short s) {
    union { unsigned int i; float f; } v; v.i = (unsigned int)s << 16; return v.f;
}
__device__ __forceinline__ unsigned short f2b(float f) {
    unsigned int u = __float_as_uint(f);
    unsigned int r = u + 0x7fffu + ((u >> 16) & 1u);   // RNE
    return (unsigned short)(r >> 16);
}

// ---------------- conversion kernels ----------------

__global__ __launch_bounds__(256) void cvt_x_pad(const float* __restrict__ x,
                                                 unsigned short* __restrict__ xb) {
    int idx = blockIdx.x * 256 + threadIdx.x;
    if (idx >= BT_ * 192) return;
    int r = idx / 192, k = idx - r * 192;
    float v = (k < F_) ? x[(size_t)r * F_ + k] : 0.f;
    xb[idx] = f2b(v);
}

// dst[n*KP + k] = bf16(src[(k0+k)*N + n]) for k<K,n<N else 0.  dst is [NP][KP].
__global__ __launch_bounds__(256) void transpose_cvt(const float* __restrict__ src,
                                                     unsigned short* __restrict__ dst,
                                                     int K, int N, int k0, int KP, int NP) {
    int idx = blockIdx.x * 256 + threadIdx.x;
    if (idx >= NP * KP) return;
    int n = idx / KP, k = idx - n * KP;
    float v = (k < K && n < N) ? src[(size_t)(k0 + k) * N + n] : 0.f;
    dst[idx] = f2b(v);
}

// bcat[d*1536 + c] = (c<1024 ? bg_d[c] : bc_d[c-1024])
__global__ __launch_bounds__(256) void biascat(const float* __restrict__ bg_f,
                                               const float* __restrict__ bc_f,
                                               const float* __restrict__ bg_b,
                                               const float* __restrict__ bc_b,
                                               float* __restrict__ bcat) {
    int idx = blockIdx.x * 256 + threadIdx.x;
    if (idx >= 2 * 1536) return;
    int d = idx / 1536, c = idx - d * 1536;
    const float* bg = d ? bg_b : bg_f;
    const float* bc = d ? bc_b : bc_f;
    bcat[idx] = (c < 1024) ? bg[c] : bc[c - 1024];
}

// ---------------- GEMM ----------------

#define BM 128
#define BN 64
#define BK 64

template<bool RELU, int OMODE, bool AMAP>
__global__ __launch_bounds__(256) void gemm_bf16(const unsigned short* __restrict__ A,
                                                 const unsigned short* __restrict__ BT,
                                                 const float* __restrict__ bias,
                                                 void* __restrict__ Out,
                                                 int K, int Nreal, int t0) {
    __shared__ __align__(16) unsigned short As[BM * BK];
    __shared__ __align__(16) unsigned short Bs[BN * BK];
    const int tid  = threadIdx.x;
    const int lane = tid & 63;
    const int w    = tid >> 6;
    const int wm   = w & 1, wn = w >> 1;
    const int l15  = lane & 15, l4 = lane >> 4;
    const int m0   = blockIdx.x * BM;
    const int n0   = blockIdx.y * BN;

    const int ar = tid >> 1, ac = (tid & 1) * 32;
    const int br = tid >> 2, bc = (tid & 3) * 16;

    size_t arow;
    {
        int r = m0 + ar;
        if (AMAP) { int rb = r / TC; int rt = r - rb * TC; arow = (size_t)rb * T_ + t0 + rt; }
        else      arow = (size_t)r;
    }

    f32x4 acc[4][2] = {};

    for (int kt = 0; kt < K; kt += BK) {
        if (kt) __syncthreads();
        {
            const unsigned short* ga = A + arow * K + kt + ac;
            us8* la = (us8*)(As + ar * BK + ac);
            #pragma unroll
            for (int j = 0; j < 4; ++j) la[j] = *(const us8*)(ga + 8 * j);
            const unsigned short* gb = BT + (size_t)(n0 + br) * K + kt + bc;
            us8* lb = (us8*)(Bs + br * BK + bc);
            #pragma unroll
            for (int j = 0; j < 2; ++j) lb[j] = *(const us8*)(gb + 8 * j);
        }
        __syncthreads();
        #pragma unroll
        for (int kk = 0; kk < BK; kk += 32) {
            bf16x8 af[4], bfr[2];
            #pragma unroll
            for (int m = 0; m < 4; ++m)
                af[m] = *(const bf16x8*)(As + (wm * 64 + m * 16 + l15) * BK + kk + l4 * 8);
            #pragma unroll
            for (int n = 0; n < 2; ++n)
                bfr[n] = *(const bf16x8*)(Bs + (wn * 32 + n * 16 + l15) * BK + kk + l4 * 8);
            #pragma unroll
            for (int m = 0; m < 4; ++m)
                #pragma unroll
                for (int n = 0; n < 2; ++n)
                    acc[m][n] = __builtin_amdgcn_mfma_f32_16x16x32_bf16(af[m], bfr[n], acc[m][n], 0, 0, 0);
        }
    }

    const int rbase = m0 + wm * 64;
    const int cb    = n0 + wn * 32;
    #pragma unroll
    for (int m = 0; m < 4; ++m) {
        #pragma unroll
        for (int n = 0; n < 2; ++n) {
            int gc = cb + n * 16 + l15;
            if (gc < Nreal) {
                float bv = bias ? bias[gc] : 0.f;
                int gr0 = rbase + m * 16 + l4 * 4;
                #pragma unroll
                for (int r = 0; r < 4; ++r) {
                    float v = acc[m][n][r] + bv;
                    if (RELU) v = fmaxf(v, 0.f);
                    int gr = gr0 + r;
                    if (OMODE == 0) {
                        ((unsigned short*)Out)[(size_t)gr * Nreal + gc] = f2b(v);
                    } else {
                        int rb = gr / TC; int rt = gr - rb * TC;
                        size_t orow = (size_t)rb * T_ + t0 + rt;
                        ((float*)Out)[orow * Nreal + gc] += v;
                    }
                }
            }
        }
    }
}

// ---------------- persistent BiGRU chunk kernel ----------------
// 32 blocks = 2 dirs x 16 col-groups, 512 threads (8 waves). Recurrent weights LDS-resident.
// Exchange via flag-array barrier PER DIRECTION (no atomic RMW): block stores its epoch to a
// padded slot; wave 0 polls all 16 slots with one 16-lane load. h broadcast is packed bf16
// (hb_glob); owner's f32 h slice persists in LDS (HOWN) across the chunk.

__global__ __launch_bounds__(512) void gru_persist(const unsigned short* __restrict__ wh_f,
                                                   const unsigned short* __restrict__ wh_b,
                                                   const unsigned short* __restrict__ Xf,
                                                   const unsigned short* __restrict__ Xb,
                                                   const int* __restrict__ seq_lens,
                                                   float* __restrict__ hf32_glob,
                                                   unsigned short* __restrict__ hb_glob,
                                                   unsigned short* __restrict__ rh_glob,
                                                   float* __restrict__ u_glob,
                                                   unsigned int* __restrict__ flags,
                                                   unsigned short* __restrict__ of,
                                                   unsigned short* __restrict__ ob,
                                                   int t0f, int t0b, int base, int init) {
    __shared__ __align__(16) unsigned short WG[64 * 512];   // gate h-weight slice [col][k], swz
    __shared__ __align__(16) unsigned short WC[32 * 512];   // cand h-weight slice [col][k], swz
    __shared__ __align__(16) unsigned short STG[32 * 512];  // h (ph1) / rh (ph2), swz
    __shared__ __align__(16) unsigned short XGs[32 * 64];   // x-gate slice [b][64]
    __shared__ __align__(16) unsigned short XCs[32 * 32];   // x-cand slice [b][32]
    __shared__ float HOWN[32][32];                          // own f32 h slice [b][local col]
    __shared__ int Ls[32];

    const int bid = blockIdx.x;
    const int dir = bid >> 4;
    const int g   = bid & 15;
    const int tid = threadIdx.x;
    const int lane = tid & 63;
    const int w   = tid >> 6;
    const int l15 = lane & 15, l4 = lane >> 4;

    const unsigned short* wh = dir ? wh_b : wh_f;
    const unsigned short* X  = dir ? Xb : Xf;
    unsigned short* out      = dir ? ob : of;
    const int t0 = dir ? t0b : t0f;
    float*          hf32 = hf32_glob + (size_t)dir * 32 * 512;
    unsigned short* hb   = hb_glob   + (size_t)dir * 32 * 512;
    unsigned short* rhg  = rh_glob   + (size_t)dir * 32 * 512;
    float*          ug   = u_glob    + (size_t)dir * 32 * 512;
    unsigned int*   flg  = flags + dir * 256;       // 16 flags x 16-u32 stride (64B pad)
    unsigned int*   myflag = flg + g * 16;
    const bool is_r = (g < 8);

    // ---- load recurrent weight slices into LDS (swizzle: byte ^= (col&7)<<4) ----
    for (int j = tid; j < 4096; j += 512) {
        int col = j >> 6, ck = j & 63;
        int dstb = col * 1024 + ((ck * 16) ^ ((col & 7) << 4));
        *(us8*)((char*)WG + dstb) = *(const us8*)(wh + (size_t)(64 * g + col) * 512 + ck * 8);
    }
    for (int j = tid; j < 2048; j += 512) {
        int col = j >> 6, ck = j & 63;
        int dstb = col * 1024 + ((ck * 16) ^ ((col & 7) << 4));
        *(us8*)((char*)WC + dstb) = *(const us8*)(wh + (size_t)(1024 + 32 * g + col) * 512 + ck * 8);
    }
    if (tid < 32) {
        int L = seq_lens[tid];
        Ls[tid] = L < 0 ? 0 : (L > T_ ? T_ : L);
    }
    for (int j = tid; j < 1024; j += 512) {
        int row = j >> 5, lc = j & 31;
        HOWN[row][lc] = init ? 0.f : hf32[row * 512 + 32 * g + lc];
    }
    // stage XGs for step 0
    {
        int tt0 = dir ? (TC - 1) : 0;
        if (tid < 256) {
            int b = tid >> 3, part = tid & 7;
            *(us8*)(XGs + b * 64 + part * 8) =
                *(const us8*)(X + ((size_t)b * TC + tt0) * 1536 + 64 * g + part * 8);
        }
    }

    const int mt = w & 1, nt = w >> 1;           // phase1 tile (8 waves: 2x4)
    const int mt2 = w & 1, nt2 = (w >> 1) & 1;   // phase2 tile (waves 0-3: 2x2)

    for (int i = 0; i < TC; ++i) {
        const int tt = dir ? (TC - 1 - i) : i;
        const int t  = t0 + tt;

        // ---- phase-1 staging: h (bf16 copy, swizzled) + x-cand slice ----
        if (init && i == 0) {
            us8 z;
            for (int e = 0; e < 8; ++e) z[e] = 0;
            for (int j = tid; j < 2048; j += 512) *((us8*)STG + j) = z;
        } else {
            for (int j = tid; j < 2048; j += 512) {
                int row = j >> 6, ck = j & 63;
                int dstb = row * 1024 + ((ck * 16) ^ ((row & 7) << 4));
                *(us8*)((char*)STG + dstb) = *(const us8*)(hb + row * 512 + ck * 8);
            }
        }
        if (tid < 128) {
            int b = tid >> 2, part = tid & 3;
            *(us8*)(XCs + b * 32 + part * 8) =
                *(const us8*)(X + ((size_t)b * TC + tt) * 1536 + 1024 + 32 * g + part * 8);
        }
        __syncthreads();

        // ---- gates MFMA: [32,512] @ [512,64] ----
        f32x4 acc = {};
        {
            const int arow = mt * 16 + l15;
            const int bcol = nt * 16 + l15;
            const int sa = (arow & 7) << 4, sb = (bcol & 7) << 4;
            const char* pa = (const char*)STG + arow * 1024;
            const char* pb = (const char*)WG + bcol * 1024;
            #pragma unroll
            for (int kk = 0; kk < 16; ++kk) {
                int kb = kk * 64 + l4 * 16;
                bf16x8 a  = *(const bf16x8*)(pa + (kb ^ sa));
                bf16x8 bf = *(const bf16x8*)(pb + (kb ^ sb));
                acc = __builtin_amdgcn_mfma_f32_16x16x32_bf16(a, bf, acc, 0, 0, 0);
            }
        }
        {
            const int colL = nt * 16 + l15;
            const int col_ru = 64 * g + colL;
            #pragma unroll
            for (int r = 0; r < 4; ++r) {
                int row = mt * 16 + l4 * 4 + r;
                float s = acc[r] + b2f(XGs[row * 64 + colL]);
                float sg = 1.f / (1.f + __expf(-s));
                if (is_r) {
                    unsigned short ho = *(const unsigned short*)((const char*)STG + row * 1024 +
                                            ((col_ru * 2) ^ ((row & 7) << 4)));
                    rhg[row * 512 + col_ru] = f2b(sg * b2f(ho));
                } else {
                    ug[row * 512 + (col_ru - 512)] = sg;
                }
            }
        }

        // ---- phase-1 barrier (flag array, per dir) ----
        {
            unsigned int tgt = (unsigned)(base + 2 * i + 1);
            __syncthreads();
            if (tid == 0) {
                __threadfence();
                __hip_atomic_store(myflag, tgt, __ATOMIC_RELEASE, __HIP_MEMORY_SCOPE_AGENT);
            }
            if (w == 0) {
                const unsigned int* fp = flg + lane * 16;
                for (;;) {
                    unsigned int v = (lane < 16)
                        ? __hip_atomic_load(fp, __ATOMIC_RELAXED, __HIP_MEMORY_SCOPE_AGENT) : tgt;
                    if (__all(v >= tgt)) break;
                    __builtin_amdgcn_s_sleep(2);
                }
                __threadfence();
            }
            __syncthreads();
        }

        // ---- phase-2 staging: rh (copy, swizzled) ----
        for (int j = tid; j < 2048; j += 512) {
            int row = j >> 6, ck = j & 63;
            int dstb = row * 1024 + ((ck * 16) ^ ((row & 7) << 4));
            *(us8*)((char*)STG + dstb) = *(const us8*)(rhg + row * 512 + ck * 8);
        }
        __syncthreads();

        // ---- candidate MFMA (waves 0-3) + XGs prefetch for i+1 (waves 4-7) ----
        if (w < 4) {
            f32x4 acc2 = {};
            const int arow = mt2 * 16 + l15;
            const int bcol = nt2 * 16 + l15;
            const int sa = (arow & 7) << 4, sb = (bcol & 7) << 4;
            const char* pa = (const char*)STG + arow * 1024;
            const char* pb = (const char*)WC + bcol * 1024;
            #pragma unroll
            for (int kk = 0; kk < 16; ++kk) {
                int kb = kk * 64 + l4 * 16;
                bf16x8 a  = *(const bf16x8*)(pa + (kb ^ sa));
                bf16x8 bf = *(const bf16x8*)(pb + (kb ^ sb));
                acc2 = __builtin_amdgcn_mfma_f32_16x16x32_bf16(a, bf, acc2, 0, 0, 0);
            }
            const int colL2 = nt2 * 16 + l15;
            const int col_c = 32 * g + colL2;
            #pragma unroll
            for (int r = 0; r < 4; ++r) {
                int row = mt2 * 16 + l4 * 4 + r;
                float s = acc2[r] + b2f(XCs[row * 32 + colL2]);
                float cv = tanhf(s);
                float uu = ug[row * 512 + col_c];
                float ho = HOWN[row][colL2];
                bool act = (t < Ls[row]);
                float hn = act ? (uu * ho + (1.f - uu) * cv) : ho;
                unsigned short hnb = f2b(hn);
                out[((size_t)row * TC + tt) * 512 + col_c] = act ? hnb : (unsigned short)0;
                hb[row * 512 + col_c] = hnb;
                HOWN[row][colL2] = hn;
            }
        } else if (i + 1 < TC) {
            int ttn = dir ? (tt - 1) : (tt + 1);
            int jd = tid - 256;
            int b = jd >> 3, part = jd & 7;
            *(us8*)(XGs + b * 64 + part * 8) =
                *(const us8*)(X + ((size_t)b * TC + ttn) * 1536 + 64 * g + part * 8);
        }

        // ---- phase-2 barrier ----
        {
            unsigned int tgt = (unsigned)(base + 2 * i + 2);
            __syncthreads();
            if (tid == 0) {
                __threadfence();
                __hip_atomic_store(myflag, tgt, __ATOMIC_RELEASE, __HIP_MEMORY_SCOPE_AGENT);
            }
            if (w == 0) {
                const unsigned int* fp = flg + lane * 16;
                for (;;) {
                    unsigned int v = (lane < 16)
                        ? __hip_atomic_load(fp, __ATOMIC_RELAXED, __HIP_MEMORY_SCOPE_AGENT) : tgt;
                    if (__all(v >= tgt)) break;
                    __builtin_amdgcn_s_sleep(2);
                }
                __threadfence();
            }
            __syncthreads();
        }
    }

    // persist own f32 h slice for next chunk
    for (int j = tid; j < 1024; j += 512) {
        int row = j >> 5, lc = j & 31;
        hf32[row * 512 + 32 * g + lc] = HOWN[row][lc];
    }
}

// ---------------- launcher ----------------

extern "C" void kernel_launch(void* const* d_in, const int* in_sizes, int n_in,
                              void* d_out, int out_size, void* d_ws, size_t ws_size,
                              hipStream_t stream) {
    (void)in_sizes; (void)n_in; (void)out_size; (void)ws_size;
    const float* x    = (const float*)d_in[0];
    const int*   seq  = (const int*)  d_in[1];
    const float* w1   = (const float*)d_in[2];
    const float* b1   = (const float*)d_in[3];
    const float* w2   = (const float*)d_in[4];
    const float* b2   = (const float*)d_in[5];
    const float* wg_f = (const float*)d_in[6];
    const float* bg_f = (const float*)d_in[7];
    const float* wc_f = (const float*)d_in[8];
    const float* bc_f = (const float*)d_in[9];
    const float* wg_b = (const float*)d_in[10];
    const float* bg_b = (const float*)d_in[11];
    const float* wc_b = (const float*)d_in[12];
    const float* bc_b = (const float*)d_in[13];
    const float* wf   = (const float*)d_in[14];
    const float* bfv  = (const float*)d_in[15];

    char* p = (char*)d_ws;
    auto alloc = [&](size_t bytes) { char* q = p; p += (bytes + 255) & ~(size_t)255; return q; };

    // persistent weight buffers
    unsigned short* w1T     = (unsigned short*)alloc(512 * 192 * 2);
    unsigned short* w2T     = (unsigned short*)alloc(512 * 512 * 2);
    unsigned short* wx_f    = (unsigned short*)alloc((size_t)1536 * 512 * 2);   // x-half (k0=0)
    unsigned short* wx_b    = (unsigned short*)alloc((size_t)1536 * 512 * 2);
    unsigned short* wh_f    = (unsigned short*)alloc((size_t)1536 * 512 * 2);   // h-half (k0=512)
    unsigned short* wh_b    = (unsigned short*)alloc((size_t)1536 * 512 * 2);
    unsigned short* wfT_top = (unsigned short*)alloc(64 * 512 * 2);
    unsigned short* wfT_bot = (unsigned short*)alloc(64 * 512 * 2);
    float*          bcat    = (float*)         alloc(2 * 1536 * 4);

    // hB persistent through chunk phase (32.8 MB)
    unsigned short* hB = (unsigned short*)alloc((size_t)BT_ * 512 * 2);

    // union region: {xb, h1} (front-end) aliases {Xf, Xb, of, ob} (chunk phase)
    char* U = alloc((size_t)MCH * 1536 * 2 * 2 + (size_t)MCH * 512 * 2 * 2);
    unsigned short* xb = (unsigned short*)U;
    unsigned short* h1 = (unsigned short*)(U + (size_t)BT_ * 192 * 2);
    unsigned short* Xf = (unsigned short*)U;
    unsigned short* Xb = (unsigned short*)(U + (size_t)MCH * 1536 * 2);
    unsigned short* of = (unsigned short*)(U + (size_t)MCH * 1536 * 2 * 2);
    unsigned short* ob = (unsigned short*)(U + (size_t)MCH * 1536 * 2 * 2 + (size_t)MCH * 512 * 2);

    // GRU state/comm (outside union)
    unsigned int*   flags    = (unsigned int*)  alloc(2 * 256 * 4);                 // 2KB, memset
    float*          hf32_gl  = (float*)         alloc((size_t)2 * 32 * 512 * 4);
    unsigned short* hb_gl    = (unsigned short*)alloc((size_t)2 * 32 * 512 * 2);
    unsigned short* rh_gl    = (unsigned short*)alloc((size_t)2 * 32 * 512 * 2);
    float*          u_gl     = (float*)         alloc((size_t)2 * 32 * 512 * 4);

    hipMemsetAsync(d_out, 0, (size_t)BT_ * C_ * 4, stream);
    hipMemsetAsync(flags, 0, 2 * 256 * 4, stream);

    // ---- weight prep ----
    transpose_cvt<<<(512 * 192) / 256, 256, 0, stream>>>(w1, w1T, 161, 512, 0, 192, 512);
    transpose_cvt<<<(512 * 512) / 256, 256, 0, stream>>>(w2, w2T, 512, 512, 0, 512, 512);
    transpose_cvt<<<(1024 * 512) / 256, 256, 0, stream>>>(wg_f, wx_f, 512, 1024, 0, 512, 1024);
    transpose_cvt<<<(512 * 512) / 256, 256, 0, stream>>>(wc_f, wx_f + (size_t)1024 * 512, 512, 512, 0, 512, 512);
    transpose_cvt<<<(1024 * 512) / 256, 256, 0, stream>>>(wg_b, wx_b, 512, 1024, 0, 512, 1024);
    transpose_cvt<<<(512 * 512) / 256, 256, 0, stream>>>(wc_b, wx_b + (size_t)1024 * 512, 512, 512, 0, 512, 512);
    transpose_cvt<<<(1024 * 512) / 256, 256, 0, stream>>>(wg_f, wh_f, 512, 1024, 512, 512, 1024);
    transpose_cvt<<<(512 * 512) / 256, 256, 0, stream>>>(wc_f, wh_f + (size_t)1024 * 512, 512, 512, 512, 512, 512);
    transpose_cvt<<<(1024 * 512) / 256, 256, 0, stream>>>(wg_b, wh_b, 512, 1024, 512, 512, 1024);
    transpose_cvt<<<(512 * 512) / 256, 256, 0, stream>>>(wc_b, wh_b + (size_t)1024 * 512, 512, 512, 512, 512, 512);
    transpose_cvt<<<(64 * 512) / 256, 256, 0, stream>>>(wf, wfT_top, 512, 62, 0, 512, 64);
    transpose_cvt<<<(64 * 512) / 256, 256, 0, stream>>>(wf, wfT_bot, 512, 62, 512, 512, 64);
    biascat<<<(2 * 1536 + 255) / 256, 256, 0, stream>>>(bg_f, bc_f, bg_b, bc_b, bcat);

    // ---- dense front-end ----
    cvt_x_pad<<<(BT_ * 192 + 255) / 256, 256, 0, stream>>>(x, xb);
    gemm_bf16<true, 0, false><<<dim3(BT_ / BM, 512 / BN), 256, 0, stream>>>(xb, w1T, b1, h1, 192, 512, 0);
    gemm_bf16<true, 0, false><<<dim3(BT_ / BM, 512 / BN), 256, 0, stream>>>(h1, w2T, b2, hB, 512, 512, 0);

    // ---- chunked BiGRU + projection ----
    for (int c = 0; c < NCH; ++c) {
        const int t0f = c * TC;
        const int t0b = (NCH - 1 - c) * TC;
        gemm_bf16<false, 0, true><<<dim3(MCH / BM, 1536 / BN), 256, 0, stream>>>(hB, wx_f, bcat,        Xf, 512, 1536, t0f);
        gemm_bf16<false, 0, true><<<dim3(MCH / BM, 1536 / BN), 256, 0, stream>>>(hB, wx_b, bcat + 1536, Xb, 512, 1536, t0b);
        gru_persist<<<NB_, 512, 0, stream>>>(wh_f, wh_b, Xf, Xb, seq, hf32_gl, hb_gl, rh_gl, u_gl,
                                             flags, of, ob, t0f, t0b, c * 2 * TC, c == 0 ? 1 : 0);
        gemm_bf16<false, 1, false><<<dim3(MCH / BM, 1), 256, 0, stream>>>(of, wfT_top, bfv,     d_out, 512, C_, t0f);
        gemm_bf16<false, 1, false><<<dim3(MCH / BM, 1), 256, 0, stream>>>(ob, wfT_bot, nullptr, d_out, 512, C_, t0b);
    }
}

// Round 9
// 9851.926 us; speedup vs baseline: 2.5768x; 1.3110x over previous
//
#include <hip/hip_runtime.h>
#include <hip/hip_bf16.h>
#include <cstdint>

#define B_  32
#define T_  1000
#define F_  161
#define H_  512
#define C_  62
#define BT_ 32000
#define TC  200          // time-chunk length
#define NCH 5            // number of chunks
#define MCH (B_ * TC)    // rows per chunk gemm = 6400
#define NB_ 32           // gru grid blocks (2 dirs x 16 col-groups)

typedef __bf16 bf16x8 __attribute__((ext_vector_type(8)));
typedef float  f32x4  __attribute__((ext_vector_type(4)));
typedef unsigned short us8 __attribute__((ext_vector_type(8)));

__device__ __forceinline__ float b2f(unsigned short s) {
    union { unsigned int i; float f; } v; v.i = (unsigned int)s << 16; return v.f;
}
__device__ __forceinline__ unsigned short f2b(float f) {
    unsigned int u = __float_as_uint(f);
    unsigned int r = u + 0x7fffu + ((u >> 16) & 1u);   // RNE
    return (unsigned short)(r >> 16);
}

// ---------------- conversion kernels ----------------

__global__ __launch_bounds__(256) void cvt_x_pad(const float* __restrict__ x,
                                                 unsigned short* __restrict__ xb) {
    int idx = blockIdx.x * 256 + threadIdx.x;
    if (idx >= BT_ * 192) return;
    int r = idx / 192, k = idx - r * 192;
    float v = (k < F_) ? x[(size_t)r * F_ + k] : 0.f;
    xb[idx] = f2b(v);
}

// dst[n*KP + k] = bf16(src[(k0+k)*N + n]) for k<K,n<N else 0.  dst is [NP][KP].
__global__ __launch_bounds__(256) void transpose_cvt(const float* __restrict__ src,
                                                     unsigned short* __restrict__ dst,
                                                     int K, int N, int k0, int KP, int NP) {
    int idx = blockIdx.x * 256 + threadIdx.x;
    if (idx >= NP * KP) return;
    int n = idx / KP, k = idx - n * KP;
    float v = (k < K && n < N) ? src[(size_t)(k0 + k) * N + n] : 0.f;
    dst[idx] = f2b(v);
}

// bcat[d*1536 + c] = (c<1024 ? bg_d[c] : bc_d[c-1024])
__global__ __launch_bounds__(256) void biascat(const float* __restrict__ bg_f,
                                               const float* __restrict__ bc_f,
                                               const float* __restrict__ bg_b,
                                               const float* __restrict__ bc_b,
                                               float* __restrict__ bcat) {
    int idx = blockIdx.x * 256 + threadIdx.x;
    if (idx >= 2 * 1536) return;
    int d = idx / 1536, c = idx - d * 1536;
    const float* bg = d ? bg_b : bg_f;
    const float* bc = d ? bc_b : bc_f;
    bcat[idx] = (c < 1024) ? bg[c] : bc[c - 1024];
}

// ---------------- GEMM ----------------

#define BM 128
#define BN 64
#define BK 64

template<bool RELU, int OMODE, bool AMAP>
__global__ __launch_bounds__(256) void gemm_bf16(const unsigned short* __restrict__ A,
                                                 const unsigned short* __restrict__ BT,
                                                 const float* __restrict__ bias,
                                                 void* __restrict__ Out,
                                                 int K, int Nreal, int t0) {
    __shared__ __align__(16) unsigned short As[BM * BK];
    __shared__ __align__(16) unsigned short Bs[BN * BK];
    const int tid  = threadIdx.x;
    const int lane = tid & 63;
    const int w    = tid >> 6;
    const int wm   = w & 1, wn = w >> 1;
    const int l15  = lane & 15, l4 = lane >> 4;
    const int m0   = blockIdx.x * BM;
    const int n0   = blockIdx.y * BN;

    const int ar = tid >> 1, ac = (tid & 1) * 32;
    const int br = tid >> 2, bc = (tid & 3) * 16;

    size_t arow;
    {
        int r = m0 + ar;
        if (AMAP) { int rb = r / TC; int rt = r - rb * TC; arow = (size_t)rb * T_ + t0 + rt; }
        else      arow = (size_t)r;
    }

    f32x4 acc[4][2] = {};

    for (int kt = 0; kt < K; kt += BK) {
        if (kt) __syncthreads();
        {
            const unsigned short* ga = A + arow * K + kt + ac;
            us8* la = (us8*)(As + ar * BK + ac);
            #pragma unroll
            for (int j = 0; j < 4; ++j) la[j] = *(const us8*)(ga + 8 * j);
            const unsigned short* gb = BT + (size_t)(n0 + br) * K + kt + bc;
            us8* lb = (us8*)(Bs + br * BK + bc);
            #pragma unroll
            for (int j = 0; j < 2; ++j) lb[j] = *(const us8*)(gb + 8 * j);
        }
        __syncthreads();
        #pragma unroll
        for (int kk = 0; kk < BK; kk += 32) {
            bf16x8 af[4], bfr[2];
            #pragma unroll
            for (int m = 0; m < 4; ++m)
                af[m] = *(const bf16x8*)(As + (wm * 64 + m * 16 + l15) * BK + kk + l4 * 8);
            #pragma unroll
            for (int n = 0; n < 2; ++n)
                bfr[n] = *(const bf16x8*)(Bs + (wn * 32 + n * 16 + l15) * BK + kk + l4 * 8);
            #pragma unroll
            for (int m = 0; m < 4; ++m)
                #pragma unroll
                for (int n = 0; n < 2; ++n)
                    acc[m][n] = __builtin_amdgcn_mfma_f32_16x16x32_bf16(af[m], bfr[n], acc[m][n], 0, 0, 0);
        }
    }

    const int rbase = m0 + wm * 64;
    const int cb    = n0 + wn * 32;
    #pragma unroll
    for (int m = 0; m < 4; ++m) {
        #pragma unroll
        for (int n = 0; n < 2; ++n) {
            int gc = cb + n * 16 + l15;
            if (gc < Nreal) {
                float bv = bias ? bias[gc] : 0.f;
                int gr0 = rbase + m * 16 + l4 * 4;
                #pragma unroll
                for (int r = 0; r < 4; ++r) {
                    float v = acc[m][n][r] + bv;
                    if (RELU) v = fmaxf(v, 0.f);
                    int gr = gr0 + r;
                    if (OMODE == 0) {
                        ((unsigned short*)Out)[(size_t)gr * Nreal + gc] = f2b(v);
                    } else {
                        int rb = gr / TC; int rt = gr - rb * TC;
                        size_t orow = (size_t)rb * T_ + t0 + rt;
                        ((float*)Out)[orow * Nreal + gc] += v;
                    }
                }
            }
        }
    }
}

// ---------------- persistent BiGRU chunk kernel ----------------
// 32 blocks = 2 dirs x 16 col-groups, 512 threads (8 waves). Recurrent weights LDS-resident.
// Block (dir,g): gate cols = r[32g..32g+32) U u[512+32g..+32); cand cols [32g..+32).
// u stays in LDS (USH) between phases -> no u exchange. h/rh broadcast as packed-bf16 words
// via RELAXED AGENT-scope atomics (coherence-point access, no acquire/release fences ->
// no L2 invalidates; X slices stay L2-cached). Barrier: per-dir flag array, relaxed atomics;
// __syncthreads provides the per-wave vmcnt(0) drain before the flag store.

__global__ __launch_bounds__(512) void gru_persist(const unsigned short* __restrict__ wh_f,
                                                   const unsigned short* __restrict__ wh_b,
                                                   const unsigned short* __restrict__ Xf,
                                                   const unsigned short* __restrict__ Xb,
                                                   const int* __restrict__ seq_lens,
                                                   float* __restrict__ hf32_glob,
                                                   unsigned int* __restrict__ hb_glob,
                                                   unsigned int* __restrict__ rh_glob,
                                                   unsigned int* __restrict__ flags,
                                                   unsigned short* __restrict__ of,
                                                   unsigned short* __restrict__ ob,
                                                   int t0f, int t0b, int base, int init) {
    __shared__ __align__(16) unsigned short WG[64 * 512];   // gate h-weights [col][k], swz
    __shared__ __align__(16) unsigned short WC[32 * 512];   // cand h-weights [col][k], swz
    __shared__ __align__(16) unsigned short STG[32 * 512];  // h (ph1) / rh (ph2), swz
    __shared__ __align__(16) unsigned short XGs[32 * 64];   // x-gate slice [b][64] (r|u)
    __shared__ __align__(16) unsigned short XCs[32 * 32];   // x-cand slice [b][32]
    __shared__ float USH[32][33];                           // u gate values [b][local col]
    __shared__ float HOWN[32][32];                          // own f32 h slice [b][local col]
    __shared__ int Ls[32];

    const int bid = blockIdx.x;
    const int dir = bid >> 4;
    const int g   = bid & 15;
    const int tid = threadIdx.x;
    const int lane = tid & 63;
    const int w   = tid >> 6;
    const int l15 = lane & 15, l4 = lane >> 4;

    const unsigned short* wh = dir ? wh_b : wh_f;
    const unsigned short* X  = dir ? Xb : Xf;
    unsigned short* out      = dir ? ob : of;
    const int t0 = dir ? t0b : t0f;
    float*        hf32 = hf32_glob + (size_t)dir * 32 * 512;
    unsigned int* hb32 = hb_glob   + (size_t)dir * 32 * 256;   // [32 rows][256 u32] = 1024B/row
    unsigned int* rh32 = rh_glob   + (size_t)dir * 32 * 256;
    unsigned int* flg  = flags + dir * 256;       // 16 flags x 16-u32 stride (64B pad)
    unsigned int* myflag = flg + g * 16;

    // ---- load recurrent weight slices into LDS (swizzle: byte ^= (col&7)<<4) ----
    for (int j = tid; j < 4096; j += 512) {
        int col = j >> 6, ck = j & 63;
        int srcc = (col < 32) ? (32 * g + col) : (512 + 32 * g + (col - 32));
        int dstb = col * 1024 + ((ck * 16) ^ ((col & 7) << 4));
        *(us8*)((char*)WG + dstb) = *(const us8*)(wh + (size_t)srcc * 512 + ck * 8);
    }
    for (int j = tid; j < 2048; j += 512) {
        int col = j >> 6, ck = j & 63;
        int dstb = col * 1024 + ((ck * 16) ^ ((col & 7) << 4));
        *(us8*)((char*)WC + dstb) = *(const us8*)(wh + (size_t)(1024 + 32 * g + col) * 512 + ck * 8);
    }
    if (tid < 32) {
        int L = seq_lens[tid];
        Ls[tid] = L < 0 ? 0 : (L > T_ ? T_ : L);
    }
    for (int j = tid; j < 1024; j += 512) {
        int row = j >> 5, lc = j & 31;
        HOWN[row][lc] = init ? 0.f : hf32[row * 512 + 32 * g + lc];
    }
    // stage XGs for step 0
    {
        int tt0 = dir ? (TC - 1) : 0;
        if (tid < 256) {
            int b = tid >> 3, part = tid & 7;
            int srcc = (part < 4) ? (32 * g + part * 8) : (512 + 32 * g + (part - 4) * 8);
            *(us8*)(XGs + b * 64 + part * 8) =
                *(const us8*)(X + ((size_t)b * TC + tt0) * 1536 + srcc);
        }
    }

    const int mt = w & 1, nt = w >> 1;           // phase1 tile (8 waves: 2x4)
    const int mt2 = w & 1, nt2 = (w >> 1) & 1;   // phase2 tile (waves 0-3: 2x2)

    for (int i = 0; i < TC; ++i) {
        const int tt = dir ? (TC - 1 - i) : i;
        const int t  = t0 + tt;

        // ---- phase-1 staging: h broadcast (relaxed u64 atomics) + x-cand slice ----
        // STG row = 1024 B = 128 u64 words; full coverage needs j < 32*128 = 4096.
        if (init && i == 0) {
            for (int j = tid; j < 4096; j += 512) {
                *(unsigned long long*)((char*)STG + j * 8) = 0ull;
            }
        } else {
            const unsigned long long* hb64 = (const unsigned long long*)hb32;
            for (int j = tid; j < 4096; j += 512) {
                int row = j >> 7, ck = j & 127;
                unsigned long long v = __hip_atomic_load(hb64 + row * 128 + ck,
                                          __ATOMIC_RELAXED, __HIP_MEMORY_SCOPE_AGENT);
                int dstb = row * 1024 + ((ck * 8) ^ ((row & 7) << 4));
                *(unsigned long long*)((char*)STG + dstb) = v;
            }
        }
        if (tid < 128) {
            int b = tid >> 2, part = tid & 3;
            *(us8*)(XCs + b * 32 + part * 8) =
                *(const us8*)(X + ((size_t)b * TC + tt) * 1536 + 1024 + 32 * g + part * 8);
        }
        __syncthreads();

        // ---- gates MFMA: [32,512] @ [512,64]  (cols: 32 r | 32 u) ----
        f32x4 acc = {};
        {
            const int arow = mt * 16 + l15;
            const int bcol = nt * 16 + l15;
            const int sa = (arow & 7) << 4, sb = (bcol & 7) << 4;
            const char* pa = (const char*)STG + arow * 1024;
            const char* pb = (const char*)WG + bcol * 1024;
            #pragma unroll
            for (int kk = 0; kk < 16; ++kk) {
                int kb = kk * 64 + l4 * 16;
                bf16x8 a  = *(const bf16x8*)(pa + (kb ^ sa));
                bf16x8 bf = *(const bf16x8*)(pb + (kb ^ sb));
                acc = __builtin_amdgcn_mfma_f32_16x16x32_bf16(a, bf, acc, 0, 0, 0);
            }
        }
        {
            const int colL = nt * 16 + l15;        // wave-uniform branch: nt<2 -> r, else u
            #pragma unroll
            for (int r = 0; r < 4; ++r) {
                int row = mt * 16 + l4 * 4 + r;
                float s = acc[r] + b2f(XGs[row * 64 + colL]);
                float sg = 1.f / (1.f + __expf(-s));
                if (colL < 32) {
                    int c = 32 * g + colL;
                    unsigned short ho = *(const unsigned short*)((const char*)STG + row * 1024 +
                                            ((c * 2) ^ ((row & 7) << 4)));
                    unsigned int pr = f2b(sg * b2f(ho));
                    unsigned int po = (unsigned int)__shfl_xor((int)pr, 1);
                    if (!(lane & 1))
                        __hip_atomic_store(rh32 + row * 256 + 16 * g + (colL >> 1),
                                           pr | (po << 16),
                                           __ATOMIC_RELAXED, __HIP_MEMORY_SCOPE_AGENT);
                } else {
                    USH[row][colL - 32] = sg;
                }
            }
        }

        // ---- phase-1 barrier (fence-free) ----
        {
            unsigned int tgt = (unsigned)(base + 2 * i + 1);
            __syncthreads();
            if (tid == 0)
                __hip_atomic_store(myflag, tgt, __ATOMIC_RELAXED, __HIP_MEMORY_SCOPE_AGENT);
            if (w == 0) {
                const unsigned int* fp = flg + lane * 16;
                for (;;) {
                    unsigned int v = (lane < 16)
                        ? __hip_atomic_load(fp, __ATOMIC_RELAXED, __HIP_MEMORY_SCOPE_AGENT) : tgt;
                    if (__all(v >= tgt)) break;
                    __builtin_amdgcn_s_sleep(1);
                }
            }
            __syncthreads();
        }

        // ---- phase-2 staging: rh broadcast (relaxed u64 atomics) ----
        {
            const unsigned long long* rh64 = (const unsigned long long*)rh32;
            for (int j = tid; j < 4096; j += 512) {
                int row = j >> 7, ck = j & 127;
                unsigned long long v = __hip_atomic_load(rh64 + row * 128 + ck,
                                          __ATOMIC_RELAXED, __HIP_MEMORY_SCOPE_AGENT);
                int dstb = row * 1024 + ((ck * 8) ^ ((row & 7) << 4));
                *(unsigned long long*)((char*)STG + dstb) = v;
            }
        }
        __syncthreads();

        // ---- candidate MFMA (waves 0-3) + XGs prefetch for i+1 (waves 4-7) ----
        if (w < 4) {
            f32x4 acc2 = {};
            const int arow = mt2 * 16 + l15;
            const int bcol = nt2 * 16 + l15;
            const int sa = (arow & 7) << 4, sb = (bcol & 7) << 4;
            const char* pa = (const char*)STG + arow * 1024;
            const char* pb = (const char*)WC + bcol * 1024;
            #pragma unroll
            for (int kk = 0; kk < 16; ++kk) {
                int kb = kk * 64 + l4 * 16;
                bf16x8 a  = *(const bf16x8*)(pa + (kb ^ sa));
                bf16x8 bf = *(const bf16x8*)(pb + (kb ^ sb));
                acc2 = __builtin_amdgcn_mfma_f32_16x16x32_bf16(a, bf, acc2, 0, 0, 0);
            }
            const int colL2 = nt2 * 16 + l15;
            const int col_c = 32 * g + colL2;
            #pragma unroll
            for (int r = 0; r < 4; ++r) {
                int row = mt2 * 16 + l4 * 4 + r;
                float s = acc2[r] + b2f(XCs[row * 32 + colL2]);
                float cv = tanhf(s);
                float uu = USH[row][colL2];
                float ho = HOWN[row][colL2];
                bool act = (t < Ls[row]);
                float hn = act ? (uu * ho + (1.f - uu) * cv) : ho;
                unsigned short hnb = f2b(hn);
                out[((size_t)row * TC + tt) * 512 + col_c] = act ? hnb : (unsigned short)0;
                unsigned int ph = hnb;
                unsigned int po = (unsigned int)__shfl_xor((int)ph, 1);
                if (!(lane & 1))
                    __hip_atomic_store(hb32 + row * 256 + 16 * g + (colL2 >> 1),
                                       ph | (po << 16),
                                       __ATOMIC_RELAXED, __HIP_MEMORY_SCOPE_AGENT);
                HOWN[row][colL2] = hn;
            }
        } else if (i + 1 < TC) {
            int ttn = dir ? (tt - 1) : (tt + 1);
            int jd = tid - 256;
            int b = jd >> 3, part = jd & 7;
            int srcc = (part < 4) ? (32 * g + part * 8) : (512 + 32 * g + (part - 4) * 8);
            *(us8*)(XGs + b * 64 + part * 8) =
                *(const us8*)(X + ((size_t)b * TC + ttn) * 1536 + srcc);
        }

        // ---- phase-2 barrier (fence-free) ----
        {
            unsigned int tgt = (unsigned)(base + 2 * i + 2);
            __syncthreads();
            if (tid == 0)
                __hip_atomic_store(myflag, tgt, __ATOMIC_RELAXED, __HIP_MEMORY_SCOPE_AGENT);
            if (w == 0) {
                const unsigned int* fp = flg + lane * 16;
                for (;;) {
                    unsigned int v = (lane < 16)
                        ? __hip_atomic_load(fp, __ATOMIC_RELAXED, __HIP_MEMORY_SCOPE_AGENT) : tgt;
                    if (__all(v >= tgt)) break;
                    __builtin_amdgcn_s_sleep(1);
                }
            }
            __syncthreads();
        }
    }

    // persist own f32 h slice for next chunk
    for (int j = tid; j < 1024; j += 512) {
        int row = j >> 5, lc = j & 31;
        hf32[row * 512 + 32 * g + lc] = HOWN[row][lc];
    }
}

// ---------------- launcher ----------------

extern "C" void kernel_launch(void* const* d_in, const int* in_sizes, int n_in,
                              void* d_out, int out_size, void* d_ws, size_t ws_size,
                              hipStream_t stream) {
    (void)in_sizes; (void)n_in; (void)out_size; (void)ws_size;
    const float* x    = (const float*)d_in[0];
    const int*   seq  = (const int*)  d_in[1];
    const float* w1   = (const float*)d_in[2];
    const float* b1   = (const float*)d_in[3];
    const float* w2   = (const float*)d_in[4];
    const float* b2   = (const float*)d_in[5];
    const float* wg_f = (const float*)d_in[6];
    const float* bg_f = (const float*)d_in[7];
    const float* wc_f = (const float*)d_in[8];
    const float* bc_f = (const float*)d_in[9];
    const float* wg_b = (const float*)d_in[10];
    const float* bg_b = (const float*)d_in[11];
    const float* wc_b = (const float*)d_in[12];
    const float* bc_b = (const float*)d_in[13];
    const float* wf   = (const float*)d_in[14];
    const float* bfv  = (const float*)d_in[15];

    char* p = (char*)d_ws;
    auto alloc = [&](size_t bytes) { char* q = p; p += (bytes + 255) & ~(size_t)255; return q; };

    // persistent weight buffers
    unsigned short* w1T     = (unsigned short*)alloc(512 * 192 * 2);
    unsigned short* w2T     = (unsigned short*)alloc(512 * 512 * 2);
    unsigned short* wx_f    = (unsigned short*)alloc((size_t)1536 * 512 * 2);   // x-half (k0=0)
    unsigned short* wx_b    = (unsigned short*)alloc((size_t)1536 * 512 * 2);
    unsigned short* wh_f    = (unsigned short*)alloc((size_t)1536 * 512 * 2);   // h-half (k0=512)
    unsigned short* wh_b    = (unsigned short*)alloc((size_t)1536 * 512 * 2);
    unsigned short* wfT_top = (unsigned short*)alloc(64 * 512 * 2);
    unsigned short* wfT_bot = (unsigned short*)alloc(64 * 512 * 2);
    float*          bcat    = (float*)         alloc(2 * 1536 * 4);

    // hB persistent through chunk phase (32.8 MB)
    unsigned short* hB = (unsigned short*)alloc((size_t)BT_ * 512 * 2);

    // union region: {xb, h1} (front-end) aliases {Xf, Xb, of, ob} (chunk phase)
    char* U = alloc((size_t)MCH * 1536 * 2 * 2 + (size_t)MCH * 512 * 2 * 2);
    unsigned short* xb = (unsigned short*)U;
    unsigned short* h1 = (unsigned short*)(U + (size_t)BT_ * 192 * 2);
    unsigned short* Xf = (unsigned short*)U;
    unsigned short* Xb = (unsigned short*)(U + (size_t)MCH * 1536 * 2);
    unsigned short* of = (unsigned short*)(U + (size_t)MCH * 1536 * 2 * 2);
    unsigned short* ob = (unsigned short*)(U + (size_t)MCH * 1536 * 2 * 2 + (size_t)MCH * 512 * 2);

    // GRU state/comm (outside union)
    unsigned int*   flags    = (unsigned int*)alloc(2 * 256 * 4);               // memset each call
    float*          hf32_gl  = (float*)       alloc((size_t)2 * 32 * 512 * 4);
    unsigned int*   hb_gl    = (unsigned int*)alloc((size_t)2 * 32 * 256 * 4);
    unsigned int*   rh_gl    = (unsigned int*)alloc((size_t)2 * 32 * 256 * 4);

    hipMemsetAsync(d_out, 0, (size_t)BT_ * C_ * 4, stream);
    hipMemsetAsync(flags, 0, 2 * 256 * 4, stream);

    // ---- weight prep ----
    transpose_cvt<<<(512 * 192) / 256, 256, 0, stream>>>(w1, w1T, 161, 512, 0, 192, 512);
    transpose_cvt<<<(512 * 512) / 256, 256, 0, stream>>>(w2, w2T, 512, 512, 0, 512, 512);
    transpose_cvt<<<(1024 * 512) / 256, 256, 0, stream>>>(wg_f, wx_f, 512, 1024, 0, 512, 1024);
    transpose_cvt<<<(512 * 512) / 256, 256, 0, stream>>>(wc_f, wx_f + (size_t)1024 * 512, 512, 512, 0, 512, 512);
    transpose_cvt<<<(1024 * 512) / 256, 256, 0, stream>>>(wg_b, wx_b, 512, 1024, 0, 512, 1024);
    transpose_cvt<<<(512 * 512) / 256, 256, 0, stream>>>(wc_b, wx_b + (size_t)1024 * 512, 512, 512, 0, 512, 512);
    transpose_cvt<<<(1024 * 512) / 256, 256, 0, stream>>>(wg_f, wh_f, 512, 1024, 512, 512, 1024);
    transpose_cvt<<<(512 * 512) / 256, 256, 0, stream>>>(wc_f, wh_f + (size_t)1024 * 512, 512, 512, 512, 512, 512);
    transpose_cvt<<<(1024 * 512) / 256, 256, 0, stream>>>(wg_b, wh_b, 512, 1024, 512, 512, 1024);
    transpose_cvt<<<(512 * 512) / 256, 256, 0, stream>>>(wc_b, wh_b + (size_t)1024 * 512, 512, 512, 512, 512, 512);
    transpose_cvt<<<(64 * 512) / 256, 256, 0, stream>>>(wf, wfT_top, 512, 62, 0, 512, 64);
    transpose_cvt<<<(64 * 512) / 256, 256, 0, stream>>>(wf, wfT_bot, 512, 62, 512, 512, 64);
    biascat<<<(2 * 1536 + 255) / 256, 256, 0, stream>>>(bg_f, bc_f, bg_b, bc_b, bcat);

    // ---- dense front-end ----
    cvt_x_pad<<<(BT_ * 192 + 255) / 256, 256, 0, stream>>>(x, xb);
    gemm_bf16<true, 0, false><<<dim3(BT_ / BM, 512 / BN), 256, 0, stream>>>(xb, w1T, b1, h1, 192, 512, 0);
    gemm_bf16<true, 0, false><<<dim3(BT_ / BM, 512 / BN), 256, 0, stream>>>(h1, w2T, b2, hB, 512, 512, 0);

    // ---- chunked BiGRU + projection ----
    for (int c = 0; c < NCH; ++c) {
        const int t0f = c * TC;
        const int t0b = (NCH - 1 - c) * TC;
        gemm_bf16<false, 0, true><<<dim3(MCH / BM, 1536 / BN), 256, 0, stream>>>(hB, wx_f, bcat,        Xf, 512, 1536, t0f);
        gemm_bf16<false, 0, true><<<dim3(MCH / BM, 1536 / BN), 256, 0, stream>>>(hB, wx_b, bcat + 1536, Xb, 512, 1536, t0b);
        gru_persist<<<NB_, 512, 0, stream>>>(wh_f, wh_b, Xf, Xb, seq, hf32_gl, hb_gl, rh_gl,
                                             flags, of, ob, t0f, t0b, c * 2 * TC, c == 0 ? 1 : 0);
        gemm_bf16<false, 1, false><<<dim3(MCH / BM, 1), 256, 0, stream>>>(of, wfT_top, bfv,     d_out, 512, C_, t0f);
        gemm_bf16<false, 1, false><<<dim3(MCH / BM, 1), 256, 0, stream>>>(ob, wfT_bot, nullptr, d_out, 512, C_, t0b);
    }
}

// Round 11
// 9283.395 us; speedup vs baseline: 2.7346x; 1.0612x over previous
//
#include <hip/hip_runtime.h>
#include <hip/hip_bf16.h>
#include <cstdint>

#define B_  32
#define T_  1000
#define F_  161
#define H_  512
#define C_  62
#define BT_ 32000
#define TC  200          // time-chunk length
#define NCH 5            // number of chunks
#define MCH (B_ * TC)    // rows per chunk gemm = 6400
#define FAST_TRIES 64    // sc0 polls before sticky agent fallback

typedef __bf16 bf16x8 __attribute__((ext_vector_type(8)));
typedef float  f32x4  __attribute__((ext_vector_type(4)));
typedef unsigned short us8 __attribute__((ext_vector_type(8)));

__device__ __forceinline__ float b2f(unsigned short s) {
    union { unsigned int i; float f; } v; v.i = (unsigned int)s << 16; return v.f;
}
__device__ __forceinline__ unsigned short f2b(float f) {
    unsigned int u = __float_as_uint(f);
    unsigned int r = u + 0x7fffu + ((u >> 16) & 1u);   // RNE
    return (unsigned short)(r >> 16);
}

// sc0 ops: intended XCD-local (bypass L1, meet in local L2). Unproven -> always paired
// with an agent-scope fallback path.
__device__ __forceinline__ unsigned int ld_sc0_u32(const unsigned int* p) {
    unsigned int v;
    asm volatile("global_load_dword %0, %1, off sc0\n\ts_waitcnt vmcnt(0)"
                 : "=&v"(v) : "v"(p) : "memory");
    return v;
}
__device__ __forceinline__ void st_sc0_u32(unsigned int* p, unsigned int v) {
    asm volatile("global_store_dword %0, %1, off sc0" :: "v"(p), "v"(v) : "memory");
}

// ---------------- conversion kernels ----------------

__global__ __launch_bounds__(256) void cvt_x_pad(const float* __restrict__ x,
                                                 unsigned short* __restrict__ xb) {
    int idx = blockIdx.x * 256 + threadIdx.x;
    if (idx >= BT_ * 192) return;
    int r = idx / 192, k = idx - r * 192;
    float v = (k < F_) ? x[(size_t)r * F_ + k] : 0.f;
    xb[idx] = f2b(v);
}

// dst[n*KP + k] = bf16(src[(k0+k)*N + n]) for k<K,n<N else 0.  dst is [NP][KP].
__global__ __launch_bounds__(256) void transpose_cvt(const float* __restrict__ src,
                                                     unsigned short* __restrict__ dst,
                                                     int K, int N, int k0, int KP, int NP) {
    int idx = blockIdx.x * 256 + threadIdx.x;
    if (idx >= NP * KP) return;
    int n = idx / KP, k = idx - n * KP;
    float v = (k < K && n < N) ? src[(size_t)(k0 + k) * N + n] : 0.f;
    dst[idx] = f2b(v);
}

// bcat[d*1536 + c] = (c<1024 ? bg_d[c] : bc_d[c-1024])
__global__ __launch_bounds__(256) void biascat(const float* __restrict__ bg_f,
                                               const float* __restrict__ bc_f,
                                               const float* __restrict__ bg_b,
                                               const float* __restrict__ bc_b,
                                               float* __restrict__ bcat) {
    int idx = blockIdx.x * 256 + threadIdx.x;
    if (idx >= 2 * 1536) return;
    int d = idx / 1536, c = idx - d * 1536;
    const float* bg = d ? bg_b : bg_f;
    const float* bc = d ? bc_b : bc_f;
    bcat[idx] = (c < 1024) ? bg[c] : bc[c - 1024];
}

// ---------------- GEMM ----------------

#define BM 128
#define BN 64
#define BK 64

template<bool RELU, int OMODE, bool AMAP>
__global__ __launch_bounds__(256) void gemm_bf16(const unsigned short* __restrict__ A,
                                                 const unsigned short* __restrict__ BT,
                                                 const float* __restrict__ bias,
                                                 void* __restrict__ Out,
                                                 int K, int Nreal, int t0) {
    __shared__ __align__(16) unsigned short As[BM * BK];
    __shared__ __align__(16) unsigned short Bs[BN * BK];
    const int tid  = threadIdx.x;
    const int lane = tid & 63;
    const int w    = tid >> 6;
    const int wm   = w & 1, wn = w >> 1;
    const int l15  = lane & 15, l4 = lane >> 4;
    const int m0   = blockIdx.x * BM;
    const int n0   = blockIdx.y * BN;

    const int ar = tid >> 1, ac = (tid & 1) * 32;
    const int br = tid >> 2, bc = (tid & 3) * 16;

    size_t arow;
    {
        int r = m0 + ar;
        if (AMAP) { int rb = r / TC; int rt = r - rb * TC; arow = (size_t)rb * T_ + t0 + rt; }
        else      arow = (size_t)r;
    }

    f32x4 acc[4][2] = {};

    for (int kt = 0; kt < K; kt += BK) {
        if (kt) __syncthreads();
        {
            const unsigned short* ga = A + arow * K + kt + ac;
            us8* la = (us8*)(As + ar * BK + ac);
            #pragma unroll
            for (int j = 0; j < 4; ++j) la[j] = *(const us8*)(ga + 8 * j);
            const unsigned short* gb = BT + (size_t)(n0 + br) * K + kt + bc;
            us8* lb = (us8*)(Bs + br * BK + bc);
            #pragma unroll
            for (int j = 0; j < 2; ++j) lb[j] = *(const us8*)(gb + 8 * j);
        }
        __syncthreads();
        #pragma unroll
        for (int kk = 0; kk < BK; kk += 32) {
            bf16x8 af[4], bfr[2];
            #pragma unroll
            for (int m = 0; m < 4; ++m)
                af[m] = *(const bf16x8*)(As + (wm * 64 + m * 16 + l15) * BK + kk + l4 * 8);
            #pragma unroll
            for (int n = 0; n < 2; ++n)
                bfr[n] = *(const bf16x8*)(Bs + (wn * 32 + n * 16 + l15) * BK + kk + l4 * 8);
            #pragma unroll
            for (int m = 0; m < 4; ++m)
                #pragma unroll
                for (int n = 0; n < 2; ++n)
                    acc[m][n] = __builtin_amdgcn_mfma_f32_16x16x32_bf16(af[m], bfr[n], acc[m][n], 0, 0, 0);
        }
    }

    const int rbase = m0 + wm * 64;
    const int cb    = n0 + wn * 32;
    #pragma unroll
    for (int m = 0; m < 4; ++m) {
        #pragma unroll
        for (int n = 0; n < 2; ++n) {
            int gc = cb + n * 16 + l15;
            if (gc < Nreal) {
                float bv = bias ? bias[gc] : 0.f;
                int gr0 = rbase + m * 16 + l4 * 4;
                #pragma unroll
                for (int r = 0; r < 4; ++r) {
                    float v = acc[m][n][r] + bv;
                    if (RELU) v = fmaxf(v, 0.f);
                    int gr = gr0 + r;
                    if (OMODE == 0) {
                        ((unsigned short*)Out)[(size_t)gr * Nreal + gc] = f2b(v);
                    } else {
                        int rb = gr / TC; int rt = gr - rb * TC;
                        size_t orow = (size_t)rb * T_ + t0 + rt;
                        ((float*)Out)[orow * Nreal + gc] += v;
                    }
                }
            }
        }
    }
}

// ---------------- persistent BiGRU chunk kernel (dual-path exchange) ----------------
// Grid = 256 blocks (1/CU via 146 KB LDS -> co-resident; 32 per XCD). Blocks on XCD d (d<2)
// claim dir d roles (16 winners via atomicAdd); rest exit. All peers of a dir share one XCD.
// Exchange dual-written: sc0 stores (fast, XCD-local L2) AND relaxed agent atomics (proven).
// Consumers poll sc0 flags; after FAST_TRIES flip sticky to the agent path (flags + data).
// Each path self-consistent (own flag orders own data; __syncthreads drains stores first).

__device__ __forceinline__ void stage_bcast(unsigned short* STG,
                                            const unsigned int* srcA,
                                            const unsigned int* srcL,
                                            int mode, int tid) {
    if (mode) {
        const unsigned long long* s64 = (const unsigned long long*)srcA;
        for (int j = tid; j < 4096; j += 512) {
            int row = j >> 7, ck = j & 127;
            unsigned long long v = __hip_atomic_load(s64 + row * 128 + ck,
                                      __ATOMIC_RELAXED, __HIP_MEMORY_SCOPE_AGENT);
            int dstb = row * 1024 + ((ck * 8) ^ ((row & 7) << 4));
            *(unsigned long long*)((char*)STG + dstb) = v;
        }
    } else {
        const int bck = tid & 127;
        const int br0 = tid >> 7;
        const unsigned long long* s64 = (const unsigned long long*)srcL;
        const unsigned long long* a0 = s64 + (br0 +  0) * 128 + bck;
        const unsigned long long* a1 = s64 + (br0 +  4) * 128 + bck;
        const unsigned long long* a2 = s64 + (br0 +  8) * 128 + bck;
        const unsigned long long* a3 = s64 + (br0 + 12) * 128 + bck;
        const unsigned long long* a4 = s64 + (br0 + 16) * 128 + bck;
        const unsigned long long* a5 = s64 + (br0 + 20) * 128 + bck;
        const unsigned long long* a6 = s64 + (br0 + 24) * 128 + bck;
        const unsigned long long* a7 = s64 + (br0 + 28) * 128 + bck;
        unsigned long long v0, v1, v2, v3, v4, v5, v6, v7;
        asm volatile(
            "global_load_dwordx2 %0, %8, off sc0\n\t"
            "global_load_dwordx2 %1, %9, off sc0\n\t"
            "global_load_dwordx2 %2, %10, off sc0\n\t"
            "global_load_dwordx2 %3, %11, off sc0\n\t"
            "global_load_dwordx2 %4, %12, off sc0\n\t"
            "global_load_dwordx2 %5, %13, off sc0\n\t"
            "global_load_dwordx2 %6, %14, off sc0\n\t"
            "global_load_dwordx2 %7, %15, off sc0\n\t"
            "s_waitcnt vmcnt(0)"
            : "=&v"(v0), "=&v"(v1), "=&v"(v2), "=&v"(v3),
              "=&v"(v4), "=&v"(v5), "=&v"(v6), "=&v"(v7)
            : "v"(a0), "v"(a1), "v"(a2), "v"(a3),
              "v"(a4), "v"(a5), "v"(a6), "v"(a7)
            : "memory");
        const int swz = bck * 8;
        *(unsigned long long*)((char*)STG + (br0 +  0) * 1024 + (swz ^ (((br0 +  0) & 7) << 4))) = v0;
        *(unsigned long long*)((char*)STG + (br0 +  4) * 1024 + (swz ^ (((br0 +  4) & 7) << 4))) = v1;
        *(unsigned long long*)((char*)STG + (br0 +  8) * 1024 + (swz ^ (((br0 +  8) & 7) << 4))) = v2;
        *(unsigned long long*)((char*)STG + (br0 + 12) * 1024 + (swz ^ (((br0 + 12) & 7) << 4))) = v3;
        *(unsigned long long*)((char*)STG + (br0 + 16) * 1024 + (swz ^ (((br0 + 16) & 7) << 4))) = v4;
        *(unsigned long long*)((char*)STG + (br0 + 20) * 1024 + (swz ^ (((br0 + 20) & 7) << 4))) = v5;
        *(unsigned long long*)((char*)STG + (br0 + 24) * 1024 + (swz ^ (((br0 + 24) & 7) << 4))) = v6;
        *(unsigned long long*)((char*)STG + (br0 + 28) * 1024 + (swz ^ (((br0 + 28) & 7) << 4))) = v7;
    }
}

__global__ __launch_bounds__(512) void gru_persist(const unsigned short* __restrict__ wh_f,
                                                   const unsigned short* __restrict__ wh_b,
                                                   const unsigned short* __restrict__ Xf,
                                                   const unsigned short* __restrict__ Xb,
                                                   const int* __restrict__ seq_lens,
                                                   float* __restrict__ hf32_glob,
                                                   unsigned int* __restrict__ hbA_g,
                                                   unsigned int* __restrict__ hbL_g,
                                                   unsigned int* __restrict__ rhA_g,
                                                   unsigned int* __restrict__ rhL_g,
                                                   unsigned int* __restrict__ flagsA,
                                                   unsigned int* __restrict__ flagsL,
                                                   int* __restrict__ claim,
                                                   unsigned short* __restrict__ of,
                                                   unsigned short* __restrict__ ob,
                                                   int t0f, int t0b, int base, int init) {
    __shared__ __align__(16) unsigned short WG[64 * 512];   // gate h-weights [col][k], swz
    __shared__ __align__(16) unsigned short WC[32 * 512];   // cand h-weights [col][k], swz
    __shared__ __align__(16) unsigned short STG[32 * 512];  // h (ph1) / rh (ph2), swz
    __shared__ __align__(16) unsigned short XGs[32 * 64];   // x-gate slice [b][64] (r|u)
    __shared__ __align__(16) unsigned short XCs[32 * 32];   // x-cand slice [b][32]
    __shared__ float USH[32][33];                           // u gate values [b][local col]
    __shared__ float HOWN[32][32];                          // own f32 h slice [b][local col]
    __shared__ int Ls[32];
    __shared__ int role_sh;
    __shared__ int mode_sh;                                 // 0 = sc0 fast, 1 = agent (sticky)

    const int tid = threadIdx.x;

    // ---- XCD-based role claim ----
    if (tid == 0) {
        unsigned int xcd;
        asm volatile("s_getreg_b32 %0, hwreg(HW_REG_XCC_ID)" : "=s"(xcd));
        xcd &= 7u;
        int r = -1;
        if (xcd < 2u) {
            int s = atomicAdd(&claim[xcd], 1);
            if (s < 16) r = (int)(xcd * 16u) + s;
        }
        role_sh = r;
        mode_sh = 0;
    }
    __syncthreads();
    const int role = role_sh;
    if (role < 0) return;
    const int dir = role >> 4;
    const int g   = role & 15;

    const int lane = tid & 63;
    const int w   = tid >> 6;
    const int l15 = lane & 15, l4 = lane >> 4;

    const unsigned short* wh = dir ? wh_b : wh_f;
    const unsigned short* X  = dir ? Xb : Xf;
    unsigned short* out      = dir ? ob : of;
    const int t0 = dir ? t0b : t0f;
    float*        hf32 = hf32_glob + (size_t)dir * 32 * 512;
    unsigned int* hbA  = hbA_g + (size_t)dir * 32 * 256;   // [32 rows][256 u32] = 1024B/row
    unsigned int* hbL  = hbL_g + (size_t)dir * 32 * 256;
    unsigned int* rhA  = rhA_g + (size_t)dir * 32 * 256;
    unsigned int* rhL  = rhL_g + (size_t)dir * 32 * 256;
    unsigned int* flgA = flagsA + dir * 256;               // 16 flags x 16-u32 stride
    unsigned int* flgL = flagsL + dir * 256;
    unsigned int* myflagA = flgA + g * 16;
    unsigned int* myflagL = flgL + g * 16;

    // ---- load recurrent weight slices into LDS (swizzle: byte ^= (col&7)<<4) ----
    for (int j = tid; j < 4096; j += 512) {
        int col = j >> 6, ck = j & 63;
        int srcc = (col < 32) ? (32 * g + col) : (512 + 32 * g + (col - 32));
        int dstb = col * 1024 + ((ck * 16) ^ ((col & 7) << 4));
        *(us8*)((char*)WG + dstb) = *(const us8*)(wh + (size_t)srcc * 512 + ck * 8);
    }
    for (int j = tid; j < 2048; j += 512) {
        int col = j >> 6, ck = j & 63;
        int dstb = col * 1024 + ((ck * 16) ^ ((col & 7) << 4));
        *(us8*)((char*)WC + dstb) = *(const us8*)(wh + (size_t)(1024 + 32 * g + col) * 512 + ck * 8);
    }
    if (tid < 32) {
        int L = seq_lens[tid];
        Ls[tid] = L < 0 ? 0 : (L > T_ ? T_ : L);
    }
    for (int j = tid; j < 1024; j += 512) {
        int row = j >> 5, lc = j & 31;
        HOWN[row][lc] = init ? 0.f : hf32[row * 512 + 32 * g + lc];
    }
    // stage XGs for step 0
    {
        int tt0 = dir ? (TC - 1) : 0;
        if (tid < 256) {
            int b = tid >> 3, part = tid & 7;
            int srcc = (part < 4) ? (32 * g + part * 8) : (512 + 32 * g + (part - 4) * 8);
            *(us8*)(XGs + b * 64 + part * 8) =
                *(const us8*)(X + ((size_t)b * TC + tt0) * 1536 + srcc);
        }
    }

    const int mt = w & 1, nt = w >> 1;           // phase1 tile (8 waves: 2x4)
    const int mt2 = w & 1, nt2 = (w >> 1) & 1;   // phase2 tile (waves 0-3: 2x2)

    for (int i = 0; i < TC; ++i) {
        const int tt = dir ? (TC - 1 - i) : i;
        const int t  = t0 + tt;

        // ---- phase-1 staging: h broadcast + x-cand slice ----
        if (init && i == 0) {
            for (int j = tid; j < 4096; j += 512)
                *(unsigned long long*)((char*)STG + j * 8) = 0ull;
        } else {
            stage_bcast(STG, hbA, hbL, mode_sh, tid);
        }
        if (tid < 128) {
            int b = tid >> 2, part = tid & 3;
            *(us8*)(XCs + b * 32 + part * 8) =
                *(const us8*)(X + ((size_t)b * TC + tt) * 1536 + 1024 + 32 * g + part * 8);
        }
        __syncthreads();

        // ---- gates MFMA: [32,512] @ [512,64]  (cols: 32 r | 32 u) ----
        f32x4 acc = {};
        {
            const int arow = mt * 16 + l15;
            const int bcol = nt * 16 + l15;
            const int sa = (arow & 7) << 4, sb2 = (bcol & 7) << 4;
            const char* pa = (const char*)STG + arow * 1024;
            const char* pb = (const char*)WG + bcol * 1024;
            #pragma unroll
            for (int kk = 0; kk < 16; ++kk) {
                int kb = kk * 64 + l4 * 16;
                bf16x8 a  = *(const bf16x8*)(pa + (kb ^ sa));
                bf16x8 bf = *(const bf16x8*)(pb + (kb ^ sb2));
                acc = __builtin_amdgcn_mfma_f32_16x16x32_bf16(a, bf, acc, 0, 0, 0);
            }
        }
        {
            const int colL = nt * 16 + l15;        // wave-uniform branch: nt<2 -> r, else u
            #pragma unroll
            for (int r = 0; r < 4; ++r) {
                int row = mt * 16 + l4 * 4 + r;
                float s = acc[r] + b2f(XGs[row * 64 + colL]);
                float sg = 1.f / (1.f + __expf(-s));
                if (colL < 32) {
                    int c = 32 * g + colL;
                    unsigned short ho = *(const unsigned short*)((const char*)STG + row * 1024 +
                                            ((c * 2) ^ ((row & 7) << 4)));
                    unsigned int pr = f2b(sg * b2f(ho));
                    unsigned int po = (unsigned int)__shfl_xor((int)pr, 1);
                    if (!(lane & 1)) {
                        unsigned int word = pr | (po << 16);
                        int off = row * 256 + 16 * g + (colL >> 1);
                        __hip_atomic_store(rhA + off, word,
                                           __ATOMIC_RELAXED, __HIP_MEMORY_SCOPE_AGENT);
                        st_sc0_u32(rhL + off, word);
                    }
                } else {
                    USH[row][colL - 32] = sg;
                }
            }
        }

        // ---- phase-1 barrier (dual-path) ----
        {
            unsigned int tgt = (unsigned)(base + 2 * i + 1);
            __syncthreads();                       // drains all data stores (vmcnt 0)
            if (tid == 0) {
                __hip_atomic_store(myflagA, tgt, __ATOMIC_RELAXED, __HIP_MEMORY_SCOPE_AGENT);
                st_sc0_u32(myflagL, tgt);
            }
            if (w == 0) {
                bool ua = (mode_sh != 0);
                int tries = 0;
                const unsigned int* fpA = flgA + lane * 16;
                const unsigned int* fpL = flgL + lane * 16;
                for (;;) {
                    unsigned int v = tgt;
                    if (lane < 16)
                        v = ua ? __hip_atomic_load(fpA, __ATOMIC_RELAXED, __HIP_MEMORY_SCOPE_AGENT)
                               : ld_sc0_u32(fpL);
                    if (__all(v >= tgt)) break;
                    if (!ua && ++tries >= FAST_TRIES) ua = true;
                    __builtin_amdgcn_s_sleep(1);
                }
                if (ua && lane == 0) mode_sh = 1;
            }
            __syncthreads();
        }

        // ---- phase-2 staging: rh broadcast ----
        stage_bcast(STG, rhA, rhL, mode_sh, tid);
        __syncthreads();

        // ---- candidate MFMA (waves 0-3) + XGs prefetch for i+1 (waves 4-7) ----
        if (w < 4) {
            f32x4 acc2 = {};
            const int arow = mt2 * 16 + l15;
            const int bcol = nt2 * 16 + l15;
            const int sa = (arow & 7) << 4, sb2 = (bcol & 7) << 4;
            const char* pa = (const char*)STG + arow * 1024;
            const char* pb = (const char*)WC + bcol * 1024;
            #pragma unroll
            for (int kk = 0; kk < 16; ++kk) {
                int kb = kk * 64 + l4 * 16;
                bf16x8 a  = *(const bf16x8*)(pa + (kb ^ sa));
                bf16x8 bf = *(const bf16x8*)(pb + (kb ^ sb2));
                acc2 = __builtin_amdgcn_mfma_f32_16x16x32_bf16(a, bf, acc2, 0, 0, 0);
            }
            const int colL2 = nt2 * 16 + l15;
            const int col_c = 32 * g + colL2;
            #pragma unroll
            for (int r = 0; r < 4; ++r) {
                int row = mt2 * 16 + l4 * 4 + r;
                float s = acc2[r] + b2f(XCs[row * 32 + colL2]);
                float cv = tanhf(s);
                float uu = USH[row][colL2];
                float ho = HOWN[row][colL2];
                bool act = (t < Ls[row]);
                float hn = act ? (uu * ho + (1.f - uu) * cv) : ho;
                unsigned short hnb = f2b(hn);
                out[((size_t)row * TC + tt) * 512 + col_c] = act ? hnb : (unsigned short)0;
                unsigned int ph = hnb;
                unsigned int po = (unsigned int)__shfl_xor((int)ph, 1);
                if (!(lane & 1)) {
                    unsigned int word = ph | (po << 16);
                    int off = row * 256 + 16 * g + (colL2 >> 1);
                    __hip_atomic_store(hbA + off, word,
                                       __ATOMIC_RELAXED, __HIP_MEMORY_SCOPE_AGENT);
                    st_sc0_u32(hbL + off, word);
                }
                HOWN[row][colL2] = hn;
            }
        } else if (i + 1 < TC) {
            int ttn = dir ? (tt - 1) : (tt + 1);
            int jd = tid - 256;
            int b = jd >> 3, part = jd & 7;
            int srcc = (part < 4) ? (32 * g + part * 8) : (512 + 32 * g + (part - 4) * 8);
            *(us8*)(XGs + b * 64 + part * 8) =
                *(const us8*)(X + ((size_t)b * TC + ttn) * 1536 + srcc);
        }

        // ---- phase-2 barrier (dual-path) ----
        {
            unsigned int tgt = (unsigned)(base + 2 * i + 2);
            __syncthreads();
            if (tid == 0) {
                __hip_atomic_store(myflagA, tgt, __ATOMIC_RELAXED, __HIP_MEMORY_SCOPE_AGENT);
                st_sc0_u32(myflagL, tgt);
            }
            if (w == 0) {
                bool ua = (mode_sh != 0);
                int tries = 0;
                const unsigned int* fpA = flgA + lane * 16;
                const unsigned int* fpL = flgL + lane * 16;
                for (;;) {
                    unsigned int v = tgt;
                    if (lane < 16)
                        v = ua ? __hip_atomic_load(fpA, __ATOMIC_RELAXED, __HIP_MEMORY_SCOPE_AGENT)
                               : ld_sc0_u32(fpL);
                    if (__all(v >= tgt)) break;
                    if (!ua && ++tries >= FAST_TRIES) ua = true;
                    __builtin_amdgcn_s_sleep(1);
                }
                if (ua && lane == 0) mode_sh = 1;
            }
            __syncthreads();
        }
    }

    // persist own f32 h slice for next chunk
    for (int j = tid; j < 1024; j += 512) {
        int row = j >> 5, lc = j & 31;
        hf32[row * 512 + 32 * g + lc] = HOWN[row][lc];
    }
}

// ---------------- launcher ----------------

extern "C" void kernel_launch(void* const* d_in, const int* in_sizes, int n_in,
                              void* d_out, int out_size, void* d_ws, size_t ws_size,
                              hipStream_t stream) {
    (void)in_sizes; (void)n_in; (void)out_size; (void)ws_size;
    const float* x    = (const float*)d_in[0];
    const int*   seq  = (const int*)  d_in[1];
    const float* w1   = (const float*)d_in[2];
    const float* b1   = (const float*)d_in[3];
    const float* w2   = (const float*)d_in[4];
    const float* b2   = (const float*)d_in[5];
    const float* wg_f = (const float*)d_in[6];
    const float* bg_f = (const float*)d_in[7];
    const float* wc_f = (const float*)d_in[8];
    const float* bc_f = (const float*)d_in[9];
    const float* wg_b = (const float*)d_in[10];
    const float* bg_b = (const float*)d_in[11];
    const float* wc_b = (const float*)d_in[12];
    const float* bc_b = (const float*)d_in[13];
    const float* wf   = (const float*)d_in[14];
    const float* bfv  = (const float*)d_in[15];

    char* p = (char*)d_ws;
    auto alloc = [&](size_t bytes) { char* q = p; p += (bytes + 255) & ~(size_t)255; return q; };

    // persistent weight buffers
    unsigned short* w1T     = (unsigned short*)alloc(512 * 192 * 2);
    unsigned short* w2T     = (unsigned short*)alloc(512 * 512 * 2);
    unsigned short* wx_f    = (unsigned short*)alloc((size_t)1536 * 512 * 2);   // x-half (k0=0)
    unsigned short* wx_b    = (unsigned short*)alloc((size_t)1536 * 512 * 2);
    unsigned short* wh_f    = (unsigned short*)alloc((size_t)1536 * 512 * 2);   // h-half (k0=512)
    unsigned short* wh_b    = (unsigned short*)alloc((size_t)1536 * 512 * 2);
    unsigned short* wfT_top = (unsigned short*)alloc(64 * 512 * 2);
    unsigned short* wfT_bot = (unsigned short*)alloc(64 * 512 * 2);
    float*          bcat    = (float*)         alloc(2 * 1536 * 4);

    // hB persistent through chunk phase (32.8 MB)
    unsigned short* hB = (unsigned short*)alloc((size_t)BT_ * 512 * 2);

    // union region: {xb, h1} (front-end) aliases {Xf, Xb, of, ob} (chunk phase)
    char* U = alloc((size_t)MCH * 1536 * 2 * 2 + (size_t)MCH * 512 * 2 * 2);
    unsigned short* xb = (unsigned short*)U;
    unsigned short* h1 = (unsigned short*)(U + (size_t)BT_ * 192 * 2);
    unsigned short* Xf = (unsigned short*)U;
    unsigned short* Xb = (unsigned short*)(U + (size_t)MCH * 1536 * 2);
    unsigned short* of = (unsigned short*)(U + (size_t)MCH * 1536 * 2 * 2);
    unsigned short* ob = (unsigned short*)(U + (size_t)MCH * 1536 * 2 * 2 + (size_t)MCH * 512 * 2);

    // GRU state/comm (outside union). flagsA|flagsL|claim contiguous for one memset.
    unsigned int*   flagsA   = (unsigned int*)alloc(2 * 256 * 4);   // 2048 B
    unsigned int*   flagsL   = (unsigned int*)alloc(2 * 256 * 4);   // 2048 B
    int*            claim    = (int*)         alloc(256);
    float*          hf32_gl  = (float*)       alloc((size_t)2 * 32 * 512 * 4);
    unsigned int*   hbA_gl   = (unsigned int*)alloc((size_t)2 * 32 * 256 * 4);
    unsigned int*   hbL_gl   = (unsigned int*)alloc((size_t)2 * 32 * 256 * 4);
    unsigned int*   rhA_gl   = (unsigned int*)alloc((size_t)2 * 32 * 256 * 4);
    unsigned int*   rhL_gl   = (unsigned int*)alloc((size_t)2 * 32 * 256 * 4);

    hipMemsetAsync(d_out, 0, (size_t)BT_ * C_ * 4, stream);
    hipMemsetAsync(flagsA, 0, 2 * 256 * 4 + 2 * 256 * 4 + 256, stream);

    // ---- weight prep ----
    transpose_cvt<<<(512 * 192) / 256, 256, 0, stream>>>(w1, w1T, 161, 512, 0, 192, 512);
    transpose_cvt<<<(512 * 512) / 256, 256, 0, stream>>>(w2, w2T, 512, 512, 0, 512, 512);
    transpose_cvt<<<(1024 * 512) / 256, 256, 0, stream>>>(wg_f, wx_f, 512, 1024, 0, 512, 1024);
    transpose_cvt<<<(512 * 512) / 256, 256, 0, stream>>>(wc_f, wx_f + (size_t)1024 * 512, 512, 512, 0, 512, 512);
    transpose_cvt<<<(1024 * 512) / 256, 256, 0, stream>>>(wg_b, wx_b, 512, 1024, 0, 512, 1024);
    transpose_cvt<<<(512 * 512) / 256, 256, 0, stream>>>(wc_b, wx_b + (size_t)1024 * 512, 512, 512, 0, 512, 512);
    transpose_cvt<<<(1024 * 512) / 256, 256, 0, stream>>>(wg_f, wh_f, 512, 1024, 512, 512, 1024);
    transpose_cvt<<<(512 * 512) / 256, 256, 0, stream>>>(wc_f, wh_f + (size_t)1024 * 512, 512, 512, 512, 512, 512);
    transpose_cvt<<<(1024 * 512) / 256, 256, 0, stream>>>(wg_b, wh_b, 512, 1024, 512, 512, 1024);
    transpose_cvt<<<(512 * 512) / 256, 256, 0, stream>>>(wc_b, wh_b + (size_t)1024 * 512, 512, 512, 512, 512, 512);
    transpose_cvt<<<(64 * 512) / 256, 256, 0, stream>>>(wf, wfT_top, 512, 62, 0, 512, 64);
    transpose_cvt<<<(64 * 512) / 256, 256, 0, stream>>>(wf, wfT_bot, 512, 62, 512, 512, 64);
    biascat<<<(2 * 1536 + 255) / 256, 256, 0, stream>>>(bg_f, bc_f, bg_b, bc_b, bcat);

    // ---- dense front-end ----
    cvt_x_pad<<<(BT_ * 192 + 255) / 256, 256, 0, stream>>>(x, xb);
    gemm_bf16<true, 0, false><<<dim3(BT_ / BM, 512 / BN), 256, 0, stream>>>(xb, w1T, b1, h1, 192, 512, 0);
    gemm_bf16<true, 0, false><<<dim3(BT_ / BM, 512 / BN), 256, 0, stream>>>(h1, w2T, b2, hB, 512, 512, 0);

    // ---- chunked BiGRU + projection ----
    for (int c = 0; c < NCH; ++c) {
        const int t0f = c * TC;
        const int t0b = (NCH - 1 - c) * TC;
        gemm_bf16<false, 0, true><<<dim3(MCH / BM, 1536 / BN), 256, 0, stream>>>(hB, wx_f, bcat,        Xf, 512, 1536, t0f);
        gemm_bf16<false, 0, true><<<dim3(MCH / BM, 1536 / BN), 256, 0, stream>>>(hB, wx_b, bcat + 1536, Xb, 512, 1536, t0b);
        gru_persist<<<256, 512, 0, stream>>>(wh_f, wh_b, Xf, Xb, seq, hf32_gl,
                                             hbA_gl, hbL_gl, rhA_gl, rhL_gl,
                                             flagsA, flagsL, claim + 2 * c, of, ob,
                                             t0f, t0b, c * 2 * TC, c == 0 ? 1 : 0);
        gemm_bf16<false, 1, false><<<dim3(MCH / BM, 1), 256, 0, stream>>>(of, wfT_top, bfv,     d_out, 512, C_, t0f);
        gemm_bf16<false, 1, false><<<dim3(MCH / BM, 1), 256, 0, stream>>>(ob, wfT_bot, nullptr, d_out, 512, C_, t0b);
    }
}